// Round 1
// baseline (1146.992 us; speedup 1.0000x reference)
//
#include <hip/hip_runtime.h>

#define DEV __device__ __forceinline__

DEV float leaky(float x) { return x >= 0.f ? x : 0.2f * x; }

// ---------------- embed: e = x @ embed_w + embed_b, write transposed layout ----------------
// x: (4,128,128,257) f32. enc[b, f*128+band, t] = e[b,band,t,f]. enc: (4,1024,128)
__global__ void embed_kernel(const float* __restrict__ x, const float* __restrict__ ew,
                             const float* __restrict__ eb, float* __restrict__ enc) {
  int wid = threadIdx.x >> 6, lane = threadIdx.x & 63;
  int row = blockIdx.x * 4 + wid;            // [0, 65536)
  int b = row >> 14, band = (row >> 7) & 127, t = row & 127;
  const float* xr = x + (long)row * 257;
  float acc[8] = {0, 0, 0, 0, 0, 0, 0, 0};
  for (int p = lane; p < 257; p += 64) {
    float xv = xr[p];
    const float4* w4 = (const float4*)(ew + p * 8);
    float4 wa = w4[0], wb = w4[1];
    acc[0] += xv * wa.x; acc[1] += xv * wa.y; acc[2] += xv * wa.z; acc[3] += xv * wa.w;
    acc[4] += xv * wb.x; acc[5] += xv * wb.y; acc[6] += xv * wb.z; acc[7] += xv * wb.w;
  }
  #pragma unroll
  for (int f = 0; f < 8; ++f) {
    #pragma unroll
    for (int off = 32; off; off >>= 1) acc[f] += __shfl_down(acc[f], off);
  }
  if (lane == 0) {
    #pragma unroll
    for (int f = 0; f < 8; ++f)
      enc[((long)b * 1024 + f * 128 + band) * 128 + t] = acc[f] + eb[f];
  }
}

// ---------------- ctx = sum over t of enc ----------------
__global__ void ctx_kernel(const float* __restrict__ enc, float* __restrict__ ctx) {
  int wid = threadIdx.x >> 6, lane = threadIdx.x & 63;
  int row = blockIdx.x * 4 + wid;  // [0, 4096)
  const float* r = enc + (long)row * 128;
  float s = r[lane] + r[lane + 64];
  #pragma unroll
  for (int off = 32; off; off >>= 1) s += __shfl_down(s, off);
  if (lane == 0) ctx[row] = s;
}

// ---------------- gemm: y(4,1024) = h(4,1024) @ w(1024,1024) + bias ----------------
// grid 32 blocks x 256 thr; block covers 32 output cols, 8 k-chunks of 128.
__global__ void gemm4_kernel(const float* __restrict__ h, const float* __restrict__ w,
                             const float* __restrict__ bias, float* __restrict__ y) {
  __shared__ float hl[4096];
  __shared__ float red[8][4][32];
  for (int i = threadIdx.x; i < 4096; i += 256) hl[i] = h[i];
  __syncthreads();
  int jl = threadIdx.x & 31, kc = threadIdx.x >> 5;
  int j = blockIdx.x * 32 + jl;
  float a0 = 0, a1 = 0, a2 = 0, a3 = 0;
  const float* wp = w + (long)kc * 128 * 1024 + j;
  const float* h0 = hl + kc * 128;
  for (int k = 0; k < 128; ++k) {
    float wv = wp[(long)k * 1024];
    a0 += h0[k] * wv;
    a1 += h0[k + 1024] * wv;
    a2 += h0[k + 2048] * wv;
    a3 += h0[k + 3072] * wv;
  }
  red[kc][0][jl] = a0; red[kc][1][jl] = a1; red[kc][2][jl] = a2; red[kc][3][jl] = a3;
  __syncthreads();
  if (threadIdx.x < 128) {
    int b = threadIdx.x >> 5, j2 = threadIdx.x & 31;
    float s = 0;
    #pragma unroll
    for (int c = 0; c < 8; ++c) s += red[c][b][j2];
    y[b * 1024 + blockIdx.x * 32 + j2] = s + bias[blockIdx.x * 32 + j2];
  }
}

// ---------------- leaky + layernorm over last dim (1024), one block per row ----------------
__global__ void act_ln_kernel(const float* __restrict__ in, const float* __restrict__ g,
                              const float* __restrict__ be, float* __restrict__ out) {
  int b = blockIdx.x;
  __shared__ float buf[1024];
  __shared__ float rs[4], rq[4];
  const float* r = in + b * 1024;
  float s = 0, q = 0;
  #pragma unroll
  for (int i = 0; i < 4; ++i) {
    int j = threadIdx.x + i * 256;
    float v = leaky(r[j]);
    buf[j] = v; s += v; q += v * v;
  }
  #pragma unroll
  for (int off = 32; off; off >>= 1) { s += __shfl_down(s, off); q += __shfl_down(q, off); }
  int wid = threadIdx.x >> 6, lane = threadIdx.x & 63;
  if (lane == 0) { rs[wid] = s; rq[wid] = q; }
  __syncthreads();
  float S = rs[0] + rs[1] + rs[2] + rs[3];
  float Q = rq[0] + rq[1] + rq[2] + rq[3];
  float mean = S * (1.f / 1024.f);
  float var = Q * (1.f / 1024.f) - mean * mean;
  float rstd = rsqrtf(var + 1e-5f);
  #pragma unroll
  for (int i = 0; i < 4; ++i) {
    int j = threadIdx.x + i * 256;
    out[b * 1024 + j] = (buf[j] - mean) * rstd * g[j] + be[j];
  }
}

// ---------------- direct conv1d, K=7, pad 3, optional 4x upsample read ----------------
// in: (B, Cin, Tout/UPS), out: (B, Cout, Tout). Each thread: NT consecutive t.
template <int UPS, int NT>
__global__ void conv_kernel(const float* __restrict__ in, const float* __restrict__ wgt,
                            const float* __restrict__ bias, float* __restrict__ out,
                            int B, int Cin, int Cout, int Tout) {
  int bco = blockIdx.x;
  int b = bco / Cout, co = bco % Cout;
  int Tin = Tout / UPS;
  int t0 = (blockIdx.y * blockDim.x + threadIdx.x) * NT;
  if (t0 >= Tout) return;
  float acc[NT];
  #pragma unroll
  for (int n = 0; n < NT; ++n) acc[n] = 0.f;
  const float* inb = in + (long)b * Cin * Tin;
  const float* wr = wgt + (long)co * Cin * 7;
  for (int ci = 0; ci < Cin; ++ci) {
    float win[NT + 6];
    const float* row = inb + (long)ci * Tin;
    #pragma unroll
    for (int jj = 0; jj < NT + 6; ++jj) {
      int u = t0 - 3 + jj;
      float v = 0.f;
      if (u >= 0 && u < Tout) v = row[UPS == 1 ? u : (u >> 2)];
      win[jj] = v;
    }
    #pragma unroll
    for (int k = 0; k < 7; ++k) {
      float wv = wr[ci * 7 + k];
      #pragma unroll
      for (int n = 0; n < NT; ++n) acc[n] += win[n + k] * wv;
    }
  }
  float bv = bias[co];
  #pragma unroll
  for (int n = 0; n < NT; ++n)
    out[((long)b * Cout + co) * Tout + t0 + n] = acc[n] + bv;
}

// ---------------- batchnorm stats -> scale/shift per channel ----------------
__global__ void bn_stats_kernel(const float* __restrict__ y, const float* __restrict__ g,
                                const float* __restrict__ be, float* __restrict__ scale,
                                float* __restrict__ shift, int B, int C, int T) {
  int co = blockIdx.x;
  float s = 0, q = 0;
  for (int b = 0; b < B; ++b) {
    const float* r = y + ((long)b * C + co) * T;
    for (int t = threadIdx.x; t < T; t += blockDim.x) { float v = r[t]; s += v; q += v * v; }
  }
  #pragma unroll
  for (int off = 32; off; off >>= 1) { s += __shfl_down(s, off); q += __shfl_down(q, off); }
  __shared__ float rs[4], rq[4];
  int wid = threadIdx.x >> 6, lane = threadIdx.x & 63;
  if (lane == 0) { rs[wid] = s; rq[wid] = q; }
  __syncthreads();
  if (threadIdx.x == 0) {
    float S = rs[0] + rs[1] + rs[2] + rs[3];
    float Q = rq[0] + rq[1] + rq[2] + rq[3];
    float n = (float)(B * T);
    float mean = S / n;
    float var = Q / n - mean * mean;
    float rstd = rsqrtf(var + 1e-5f);
    float sc = g[co] * rstd;
    scale[co] = sc;
    shift[co] = be[co] - mean * sc;
  }
}

// ---------------- apply bn (scale/shift) + leaky, in place ----------------
__global__ void bn_apply_kernel(float* __restrict__ y, const float* __restrict__ scale,
                                const float* __restrict__ shift, int C, int T, int total) {
  int i = blockIdx.x * blockDim.x + threadIdx.x;
  if (i >= total) return;
  int co = (i / T) % C;
  y[i] = leaky(y[i] * scale[co] + shift[co]);
}

extern "C" void kernel_launch(void* const* d_in, const int* in_sizes, int n_in,
                              void* d_out, int out_size, void* d_ws, size_t ws_size,
                              hipStream_t stream) {
  const float* x     = (const float*)d_in[0];
  // d_in[1] = atoms: dead code (sparse_code result unused)
  const float* ew    = (const float*)d_in[2];
  const float* eb    = (const float*)d_in[3];
  const float* w1    = (const float*)d_in[4];
  const float* b1    = (const float*)d_in[5];
  const float* g1    = (const float*)d_in[6];
  const float* be1   = (const float*)d_in[7];
  const float* w2    = (const float*)d_in[8];
  const float* b2    = (const float*)d_in[9];
  const float* g2    = (const float*)d_in[10];
  const float* be2   = (const float*)d_in[11];
  const float* w3    = (const float*)d_in[12];
  const float* b3    = (const float*)d_in[13];
  const float* up_w1 = (const float*)d_in[14];
  const float* up_b1 = (const float*)d_in[15];
  const float* bn_g1 = (const float*)d_in[16];
  const float* bn_b1 = (const float*)d_in[17];
  const float* up_w2 = (const float*)d_in[18];
  const float* up_b2 = (const float*)d_in[19];
  const float* bn_g2 = (const float*)d_in[20];
  const float* bn_b2 = (const float*)d_in[21];
  const float* up_w3 = (const float*)d_in[22];
  const float* up_b3 = (const float*)d_in[23];
  const float* bn_g3 = (const float*)d_in[24];
  const float* bn_b3 = (const float*)d_in[25];
  const float* up_w4 = (const float*)d_in[26];
  const float* up_b4 = (const float*)d_in[27];
  const float* bn_g4 = (const float*)d_in[28];
  const float* bn_b4 = (const float*)d_in[29];
  const float* up_w5 = (const float*)d_in[30];
  const float* up_b5 = (const float*)d_in[31];

  float* out = (float*)d_out;          // [0,131072) = y, [131072,135168) = ctx_out
  float* ws = (float*)d_ws;
  float* enc   = ws;                 // 524288
  float* c1    = enc + 524288;       // 262144
  float* c2    = c1 + 262144;        // 524288
  float* c3    = c2 + 524288;        // 1048576
  float* c4    = c3 + 1048576;       // 2097152
  float* ctxb  = c4 + 2097152;       // 4096
  float* t1    = ctxb + 4096;        // 4096
  float* t2    = t1 + 4096;          // 4096
  float* scale = t2 + 4096;          // 512
  float* shift = scale + 512;        // 512

  // embed + transpose
  embed_kernel<<<16384, 256, 0, stream>>>(x, ew, eb, enc);
  // ctx path
  ctx_kernel<<<1024, 256, 0, stream>>>(enc, ctxb);
  gemm4_kernel<<<32, 256, 0, stream>>>(ctxb, w1, b1, t1);
  act_ln_kernel<<<4, 256, 0, stream>>>(t1, g1, be1, t2);
  gemm4_kernel<<<32, 256, 0, stream>>>(t2, w2, b2, t1);
  act_ln_kernel<<<4, 256, 0, stream>>>(t1, g2, be2, t2);
  gemm4_kernel<<<32, 256, 0, stream>>>(t2, w3, b3, out + 131072);

  // conv path (upsample fused into conv reads; bn folded to scale/shift)
  conv_kernel<1, 2><<<dim3(4 * 512, 1), 64, 0, stream>>>(enc, up_w1, up_b1, c1, 4, 1024, 512, 128);
  bn_stats_kernel<<<512, 256, 0, stream>>>(c1, bn_g1, bn_b1, scale, shift, 4, 512, 128);
  bn_apply_kernel<<<(262144 + 255) / 256, 256, 0, stream>>>(c1, scale, shift, 512, 128, 262144);

  conv_kernel<4, 4><<<dim3(4 * 256, 1), 128, 0, stream>>>(c1, up_w2, up_b2, c2, 4, 512, 256, 512);
  bn_stats_kernel<<<256, 256, 0, stream>>>(c2, bn_g2, bn_b2, scale, shift, 4, 256, 512);
  bn_apply_kernel<<<(524288 + 255) / 256, 256, 0, stream>>>(c2, scale, shift, 256, 512, 524288);

  conv_kernel<4, 4><<<dim3(4 * 128, 2), 256, 0, stream>>>(c2, up_w3, up_b3, c3, 4, 256, 128, 2048);
  bn_stats_kernel<<<128, 256, 0, stream>>>(c3, bn_g3, bn_b3, scale, shift, 4, 128, 2048);
  bn_apply_kernel<<<(1048576 + 255) / 256, 256, 0, stream>>>(c3, scale, shift, 128, 2048, 1048576);

  conv_kernel<4, 4><<<dim3(4 * 64, 8), 256, 0, stream>>>(c3, up_w4, up_b4, c4, 4, 128, 64, 8192);
  bn_stats_kernel<<<64, 256, 0, stream>>>(c4, bn_g4, bn_b4, scale, shift, 4, 64, 8192);
  bn_apply_kernel<<<(2097152 + 255) / 256, 256, 0, stream>>>(c4, scale, shift, 64, 8192, 2097152);

  conv_kernel<4, 4><<<dim3(4, 32), 256, 0, stream>>>(c4, up_w5, up_b5, out, 4, 64, 1, 32768);
}

// Round 2
// 350.548 us; speedup vs baseline: 3.2720x; 3.2720x over previous
//
#include <hip/hip_runtime.h>
#include <hip/hip_bf16.h>

using sh8   = __attribute__((ext_vector_type(8))) short;
using f32x4 = __attribute__((ext_vector_type(4))) float;

#define DEV __device__ __forceinline__

DEV float leaky(float x) { return x >= 0.f ? x : 0.2f * x; }

DEV unsigned short f2bf(float f) {  // round-to-nearest-even f32 -> bf16 bits
  unsigned u = __float_as_uint(f);
  u += 0x7FFF + ((u >> 16) & 1);
  return (unsigned short)(u >> 16);
}
DEV float bf2f(unsigned short b) { return __uint_as_float(((unsigned)b) << 16); }

// ---------------- embed: e = x @ embed_w + embed_b, transposed; f32 + bf16 copies ----------------
__global__ void embed_kernel(const float* __restrict__ x, const float* __restrict__ ew,
                             const float* __restrict__ eb, float* __restrict__ enc,
                             unsigned short* __restrict__ encbf) {
  int wid = threadIdx.x >> 6, lane = threadIdx.x & 63;
  int row = blockIdx.x * 4 + wid;            // [0, 65536)
  int b = row >> 14, band = (row >> 7) & 127, t = row & 127;
  const float* xr = x + (long)row * 257;
  float acc[8] = {0, 0, 0, 0, 0, 0, 0, 0};
  for (int p = lane; p < 257; p += 64) {
    float xv = xr[p];
    const float4* w4 = (const float4*)(ew + p * 8);
    float4 wa = w4[0], wb = w4[1];
    acc[0] += xv * wa.x; acc[1] += xv * wa.y; acc[2] += xv * wa.z; acc[3] += xv * wa.w;
    acc[4] += xv * wb.x; acc[5] += xv * wb.y; acc[6] += xv * wb.z; acc[7] += xv * wb.w;
  }
  #pragma unroll
  for (int f = 0; f < 8; ++f) {
    #pragma unroll
    for (int off = 32; off; off >>= 1) acc[f] += __shfl_down(acc[f], off);
  }
  if (lane == 0) {
    #pragma unroll
    for (int f = 0; f < 8; ++f) {
      float v = acc[f] + eb[f];
      long idx = ((long)b * 1024 + f * 128 + band) * 128 + t;
      enc[idx] = v;
      encbf[idx] = f2bf(v);
    }
  }
}

// ---------------- ctx = sum over t of enc ----------------
__global__ void ctx_kernel(const float* __restrict__ enc, float* __restrict__ ctx) {
  int wid = threadIdx.x >> 6, lane = threadIdx.x & 63;
  int row = blockIdx.x * 4 + wid;  // [0, 4096)
  const float* r = enc + (long)row * 128;
  float s = r[lane] + r[lane + 64];
  #pragma unroll
  for (int off = 32; off; off >>= 1) s += __shfl_down(s, off);
  if (lane == 0) ctx[row] = s;
}

// ---------------- gemm: y(4,1024) = h(4,1024) @ w(1024,1024) + bias ----------------
__global__ void gemm4_kernel(const float* __restrict__ h, const float* __restrict__ w,
                             const float* __restrict__ bias, float* __restrict__ y) {
  __shared__ float hl[4096];
  __shared__ float red[8][4][32];
  for (int i = threadIdx.x; i < 4096; i += 256) hl[i] = h[i];
  __syncthreads();
  int jl = threadIdx.x & 31, kc = threadIdx.x >> 5;
  int j = blockIdx.x * 32 + jl;
  float a0 = 0, a1 = 0, a2 = 0, a3 = 0;
  const float* wp = w + (long)kc * 128 * 1024 + j;
  const float* h0 = hl + kc * 128;
  for (int k = 0; k < 128; ++k) {
    float wv = wp[(long)k * 1024];
    a0 += h0[k] * wv;
    a1 += h0[k + 1024] * wv;
    a2 += h0[k + 2048] * wv;
    a3 += h0[k + 3072] * wv;
  }
  red[kc][0][jl] = a0; red[kc][1][jl] = a1; red[kc][2][jl] = a2; red[kc][3][jl] = a3;
  __syncthreads();
  if (threadIdx.x < 128) {
    int b = threadIdx.x >> 5, j2 = threadIdx.x & 31;
    float s = 0;
    #pragma unroll
    for (int c = 0; c < 8; ++c) s += red[c][b][j2];
    y[b * 1024 + blockIdx.x * 32 + j2] = s + bias[blockIdx.x * 32 + j2];
  }
}

// ---------------- leaky + layernorm over last dim (1024) ----------------
__global__ void act_ln_kernel(const float* __restrict__ in, const float* __restrict__ g,
                              const float* __restrict__ be, float* __restrict__ out) {
  int b = blockIdx.x;
  __shared__ float buf[1024];
  __shared__ float rs[4], rq[4];
  const float* r = in + b * 1024;
  float s = 0, q = 0;
  #pragma unroll
  for (int i = 0; i < 4; ++i) {
    int j = threadIdx.x + i * 256;
    float v = leaky(r[j]);
    buf[j] = v; s += v; q += v * v;
  }
  #pragma unroll
  for (int off = 32; off; off >>= 1) { s += __shfl_down(s, off); q += __shfl_down(q, off); }
  int wid = threadIdx.x >> 6, lane = threadIdx.x & 63;
  if (lane == 0) { rs[wid] = s; rq[wid] = q; }
  __syncthreads();
  float S = rs[0] + rs[1] + rs[2] + rs[3];
  float Q = rq[0] + rq[1] + rq[2] + rq[3];
  float mean = S * (1.f / 1024.f);
  float var = Q * (1.f / 1024.f) - mean * mean;
  float rstd = rsqrtf(var + 1e-5f);
  #pragma unroll
  for (int i = 0; i < 4; ++i) {
    int j = threadIdx.x + i * 256;
    out[b * 1024 + j] = (buf[j] - mean) * rstd * g[j] + be[j];
  }
}

// ---------------- weight pack: f32 [Cout][Cin][7] -> bf16 [7][Cin/32][Cout][32] ----------------
__global__ void wcvt_kernel(const float* __restrict__ w, unsigned short* __restrict__ wpack,
                            int Cout, int Cin) {
  int n = Cout * Cin * 7;
  int nCib = Cin >> 5;
  for (int i = blockIdx.x * blockDim.x + threadIdx.x; i < n; i += gridDim.x * blockDim.x) {
    int co = i / (Cin * 7);
    int r  = i - co * (Cin * 7);
    int ci = r / 7;
    int k  = r - ci * 7;
    wpack[((long)(k * nCib + (ci >> 5)) * Cout + co) * 32 + (ci & 31)] = f2bf(w[i]);
  }
}

// ---------------- implicit-GEMM conv1d via MFMA bf16 ----------------
// act: bf16 (B,Cin,Tin); wpack: bf16 [7][Cin/32][Cout][32]; outp: f32 (SPLITK,B,Cout,Tout)
// block: 256 thr = 4 waves; tile 64co x 64t per batch; LDS holds full ci-range x t-window.
template<int UPS, int SPLITK>
__global__ __launch_bounds__(256, 2)
void conv_mfma(const unsigned short* __restrict__ act,
               const unsigned short* __restrict__ wpack,
               float* __restrict__ outp,
               int Cin, int Cout, int Tout) {
  constexpr int NC = (UPS == 1) ? 70 : 18;   // staged source columns per tile
  const int Tin = Tout / UPS;
  const int cpb = Cin / SPLITK;              // ci handled by this block
  const int ncib = cpb >> 5;
  const int nCibTot = Cin >> 5;
  const int nco = Cout >> 6, nt = Tout >> 6;

  int bid = blockIdx.x;
  const int sk = bid % SPLITK; bid /= SPLITK;
  const int tt = bid % nt;  bid /= nt;
  const int cot = bid % nco; bid /= nco;
  const int b = bid;
  const int t0 = tt << 6, co0 = cot << 6;
  const int ci0 = sk * cpb;

  extern __shared__ unsigned short lin[];    // [ncib][NC][40] (rows padded to 80B)

  // ---- stage input window (zero-fill OOB columns handles conv padding exactly) ----
  const unsigned short* actb = act + ((long)b * Cin + ci0) * Tin;
  const int u_base = (UPS == 1) ? (t0 - 3) : ((t0 >> 2) - 1);
  const int total = cpb * NC;
  for (int i = threadIdx.x; i < total; i += 256) {
    int ci = i / NC, ul = i - ci * NC;
    int u = u_base + ul;
    unsigned short v = 0;
    if (u >= 0 && u < Tin) v = actb[(long)ci * Tin + u];
    lin[((ci >> 5) * NC + ul) * 40 + (ci & 31)] = v;
  }
  __syncthreads();

  const int lane = threadIdx.x & 63, w = threadIdx.x >> 6;
  const int m = lane & 15, g = lane >> 4;

  // per-(s,k) LDS row offsets (ushort units), hoisted out of the K loop
  int boff[28];
  #pragma unroll
  for (int s = 0; s < 4; ++s) {
    #pragma unroll
    for (int k = 0; k < 7; ++k) {
      int row = (UPS == 1) ? (s * 16 + m + k)
                           : (s * 4 + ((m + k + 9) >> 2) - 2);  // = floor((s16+m+k-3)/4)+1
      boff[s * 7 + k] = row * 40 + g * 8;
    }
  }

  const long wlane = ((long)(co0 + w * 16 + m) * 4 + g) * 8;

  f32x4 acc[4];
  #pragma unroll
  for (int s = 0; s < 4; ++s) { acc[s][0] = 0.f; acc[s][1] = 0.f; acc[s][2] = 0.f; acc[s][3] = 0.f; }

  for (int cib = 0; cib < ncib; ++cib) {
    const unsigned short* lb = lin + cib * (NC * 40);
    const int cg = (ci0 >> 5) + cib;
    sh8 a[7];
    #pragma unroll
    for (int k = 0; k < 7; ++k)
      a[k] = *(const sh8*)(wpack + (long)(k * nCibTot + cg) * Cout * 32 + wlane);
    #pragma unroll
    for (int k = 0; k < 7; ++k) {
      #pragma unroll
      for (int s = 0; s < 4; ++s) {
        sh8 bfr = *(const sh8*)(lb + boff[s * 7 + k]);
        acc[s] = __builtin_amdgcn_mfma_f32_16x16x32_bf16(a[k], bfr, acc[s], 0, 0, 0);
      }
    }
  }

  // D layout: row(co) = g*4 + r, col(t) = m
  float* op = outp + (((long)sk * 4 + b) * Cout + (co0 + w * 16 + g * 4)) * (long)Tout + t0 + m;
  #pragma unroll
  for (int r = 0; r < 4; ++r) {
    #pragma unroll
    for (int s = 0; s < 4; ++s)
      op[(long)r * Tout + s * 16] = acc[s][r];
  }
}

// ---------------- batchnorm stats over split-K partials -> scale/shift ----------------
__global__ void bn_stats(const float* __restrict__ p, const float* __restrict__ g,
                         const float* __restrict__ be, float* __restrict__ scale,
                         float* __restrict__ shift, int C, int T, int SK) {
  int co = blockIdx.x;
  long stride = (long)4 * C * T;
  float s = 0, q = 0;
  for (int b = 0; b < 4; ++b) {
    const float* r = p + ((long)b * C + co) * T;
    for (int t = threadIdx.x; t < T; t += blockDim.x) {
      float v = r[t];
      for (int k2 = 1; k2 < SK; ++k2) v += r[t + k2 * stride];
      s += v; q += v * v;
    }
  }
  #pragma unroll
  for (int off = 32; off; off >>= 1) { s += __shfl_down(s, off); q += __shfl_down(q, off); }
  __shared__ float rs[4], rq[4];
  int wid = threadIdx.x >> 6, lane = threadIdx.x & 63;
  if (lane == 0) { rs[wid] = s; rq[wid] = q; }
  __syncthreads();
  if (threadIdx.x == 0) {
    float S = rs[0] + rs[1] + rs[2] + rs[3];
    float Q = rq[0] + rq[1] + rq[2] + rq[3];
    float n = (float)(4 * T);
    float mean = S / n;
    float var = Q / n - mean * mean;
    float rstd = rsqrtf(var + 1e-5f);
    float sc = g[co] * rstd;
    scale[co] = sc;
    shift[co] = be[co] - mean * sc;
  }
}

// ---------------- apply bn + leaky, sum split-K partials, emit bf16 ----------------
__global__ void bn_apply(const float* __restrict__ p, const float* __restrict__ scale,
                         const float* __restrict__ shift, unsigned short* __restrict__ outbf,
                         int C, int T, int total, int SK) {
  int i = blockIdx.x * blockDim.x + threadIdx.x;
  if (i >= total) return;
  float v = p[i];
  for (int k = 1; k < SK; ++k) v += p[i + (long)k * total];
  int co = (i / T) % C;
  outbf[i] = f2bf(leaky(v * scale[co] + shift[co]));
}

// ---------------- final conv: Cin=64, Cout=1, UPS=4, bf16 in, f32 out ----------------
__global__ void conv5_kernel(const unsigned short* __restrict__ in, const float* __restrict__ wgt,
                             const float* __restrict__ bias, float* __restrict__ out, int Tout) {
  int b = blockIdx.y;
  int t0 = (blockIdx.x * blockDim.x + threadIdx.x) * 4;
  if (t0 >= Tout) return;
  int Tin = Tout >> 2;
  const unsigned short* inb = in + (long)b * 64 * Tin;
  float acc[4] = {0, 0, 0, 0};
  for (int ci = 0; ci < 64; ++ci) {
    const unsigned short* row = inb + (long)ci * Tin;
    float win[10];
    #pragma unroll
    for (int jj = 0; jj < 10; ++jj) {
      int tt = t0 - 3 + jj;
      win[jj] = (tt >= 0 && tt < Tout) ? bf2f(row[tt >> 2]) : 0.f;
    }
    #pragma unroll
    for (int k = 0; k < 7; ++k) {
      float wv = wgt[ci * 7 + k];
      #pragma unroll
      for (int n = 0; n < 4; ++n) acc[n] += win[n + k] * wv;
    }
  }
  float bv = bias[0];
  #pragma unroll
  for (int n = 0; n < 4; ++n) out[(long)b * Tout + t0 + n] = acc[n] + bv;
}

extern "C" void kernel_launch(void* const* d_in, const int* in_sizes, int n_in,
                              void* d_out, int out_size, void* d_ws, size_t ws_size,
                              hipStream_t stream) {
  const float* x     = (const float*)d_in[0];
  // d_in[1] = atoms: dead code (sparse_code result unused by outputs)
  const float* ew    = (const float*)d_in[2];
  const float* eb    = (const float*)d_in[3];
  const float* w1    = (const float*)d_in[4];
  const float* b1    = (const float*)d_in[5];
  const float* g1    = (const float*)d_in[6];
  const float* be1   = (const float*)d_in[7];
  const float* w2    = (const float*)d_in[8];
  const float* b2    = (const float*)d_in[9];
  const float* g2    = (const float*)d_in[10];
  const float* be2   = (const float*)d_in[11];
  const float* w3    = (const float*)d_in[12];
  const float* b3    = (const float*)d_in[13];
  const float* up_w1 = (const float*)d_in[14];
  const float* up_b1 = (const float*)d_in[15];
  const float* bn_g1 = (const float*)d_in[16];
  const float* bn_b1 = (const float*)d_in[17];
  const float* up_w2 = (const float*)d_in[18];
  const float* up_b2 = (const float*)d_in[19];
  const float* bn_g2 = (const float*)d_in[20];
  const float* bn_b2 = (const float*)d_in[21];
  const float* up_w3 = (const float*)d_in[22];
  const float* up_b3 = (const float*)d_in[23];
  const float* bn_g3 = (const float*)d_in[24];
  const float* bn_b3 = (const float*)d_in[25];
  const float* up_w4 = (const float*)d_in[26];
  const float* up_b4 = (const float*)d_in[27];
  const float* bn_g4 = (const float*)d_in[28];
  const float* bn_b4 = (const float*)d_in[29];
  const float* up_w5 = (const float*)d_in[30];
  const float* up_b5 = (const float*)d_in[31];

  float* out = (float*)d_out;          // [0,131072) = y, [131072,135168) = ctx_out

  float* ws = (float*)d_ws;
  float* enc   = ws;                          // 524288 f32
  float* ctxb  = enc + 524288;                // 4096
  float* t1    = ctxb + 4096;                 // 4096
  float* t2    = t1 + 4096;                   // 4096
  float* scale = t2 + 4096;                   // 512
  float* shift = scale + 512;                 // 512
  float* pbuf  = shift + 512;                 // 2097152 f32 (max over stages, incl. split-K)
  unsigned short* encbf = (unsigned short*)(pbuf + 2097152);  // 524288
  unsigned short* actA  = encbf + 524288;     // 2097152
  unsigned short* actB  = actA + 2097152;     // 1048576
  unsigned short* wbuf  = actB + 1048576;     // 3670016 (max weight pack)
  // total ws use ~25.2 MB

  embed_kernel<<<16384, 256, 0, stream>>>(x, ew, eb, enc, encbf);

  // ctx path (f32 throughout)
  ctx_kernel<<<1024, 256, 0, stream>>>(enc, ctxb);
  gemm4_kernel<<<32, 256, 0, stream>>>(ctxb, w1, b1, t1);
  act_ln_kernel<<<4, 256, 0, stream>>>(t1, g1, be1, t2);
  gemm4_kernel<<<32, 256, 0, stream>>>(t2, w2, b2, t1);
  act_ln_kernel<<<4, 256, 0, stream>>>(t1, g2, be2, t2);
  gemm4_kernel<<<32, 256, 0, stream>>>(t2, w3, b3, out + 131072);

  // ---- conv stage 1: (4,1024,128) -> (4,512,128), UPS=1, split-K=4 ----
  wcvt_kernel<<<2048, 256, 0, stream>>>(up_w1, wbuf, 512, 1024);
  conv_mfma<1, 4><<<256, 256, 44800, stream>>>(encbf, wbuf, pbuf, 1024, 512, 128);
  bn_stats<<<512, 256, 0, stream>>>(pbuf, bn_g1, bn_b1, scale, shift, 512, 128, 4);
  bn_apply<<<1024, 256, 0, stream>>>(pbuf, scale, shift, actB, 512, 128, 262144, 4);

  // ---- conv stage 2: (4,512,128) -up4-> (4,256,512), split-K=2 ----
  wcvt_kernel<<<2048, 256, 0, stream>>>(up_w2, wbuf, 256, 512);
  conv_mfma<4, 2><<<256, 256, 11520, stream>>>(actB, wbuf, pbuf, 512, 256, 512);
  bn_stats<<<256, 256, 0, stream>>>(pbuf, bn_g2, bn_b2, scale, shift, 256, 512, 2);
  bn_apply<<<2048, 256, 0, stream>>>(pbuf, scale, shift, actA, 256, 512, 524288, 2);

  // ---- conv stage 3: (4,256,512) -up4-> (4,128,2048) ----
  wcvt_kernel<<<2048, 256, 0, stream>>>(up_w3, wbuf, 128, 256);
  conv_mfma<4, 1><<<256, 256, 11520, stream>>>(actA, wbuf, pbuf, 256, 128, 2048);
  bn_stats<<<128, 256, 0, stream>>>(pbuf, bn_g3, bn_b3, scale, shift, 128, 2048, 1);
  bn_apply<<<4096, 256, 0, stream>>>(pbuf, scale, shift, actB, 128, 2048, 1048576, 1);

  // ---- conv stage 4: (4,128,2048) -up4-> (4,64,8192) ----
  wcvt_kernel<<<2048, 256, 0, stream>>>(up_w4, wbuf, 64, 128);
  conv_mfma<4, 1><<<512, 256, 5760, stream>>>(actB, wbuf, pbuf, 128, 64, 8192);
  bn_stats<<<64, 256, 0, stream>>>(pbuf, bn_g4, bn_b4, scale, shift, 64, 8192, 1);
  bn_apply<<<8192, 256, 0, stream>>>(pbuf, scale, shift, actA, 64, 8192, 2097152, 1);

  // ---- conv stage 5: (4,64,8192) -up4-> (4,1,32768), direct f32 ----
  conv5_kernel<<<dim3(32, 4), 256, 0, stream>>>(actA, up_w5, up_b5, out, 32768);
}

// Round 3
// 276.027 us; speedup vs baseline: 4.1554x; 1.2700x over previous
//
#include <hip/hip_runtime.h>
#include <hip/hip_bf16.h>

using sh8   = __attribute__((ext_vector_type(8))) short;
using f32x4 = __attribute__((ext_vector_type(4))) float;

#define DEV __device__ __forceinline__

DEV float leaky(float x) { return x >= 0.f ? x : 0.2f * x; }

DEV unsigned short f2bf(float f) {  // round-to-nearest-even f32 -> bf16 bits
  unsigned u = __float_as_uint(f);
  u += 0x7FFF + ((u >> 16) & 1);
  return (unsigned short)(u >> 16);
}
DEV float bf2f(unsigned short b) { return __uint_as_float(((unsigned)b) << 16); }

// ---------------- embed: e = x @ embed_w + embed_b, transposed; f32 + bf16 copies ----------------
__global__ void embed_kernel(const float* __restrict__ x, const float* __restrict__ ew,
                             const float* __restrict__ eb, float* __restrict__ enc,
                             unsigned short* __restrict__ encbf) {
  int wid = threadIdx.x >> 6, lane = threadIdx.x & 63;
  int row = blockIdx.x * 4 + wid;            // [0, 65536)
  int b = row >> 14, band = (row >> 7) & 127, t = row & 127;
  const float* xr = x + (long)row * 257;
  float acc[8] = {0, 0, 0, 0, 0, 0, 0, 0};
  for (int p = lane; p < 257; p += 64) {
    float xv = xr[p];
    const float4* w4 = (const float4*)(ew + p * 8);
    float4 wa = w4[0], wb = w4[1];
    acc[0] += xv * wa.x; acc[1] += xv * wa.y; acc[2] += xv * wa.z; acc[3] += xv * wa.w;
    acc[4] += xv * wb.x; acc[5] += xv * wb.y; acc[6] += xv * wb.z; acc[7] += xv * wb.w;
  }
  #pragma unroll
  for (int f = 0; f < 8; ++f) {
    #pragma unroll
    for (int off = 32; off; off >>= 1) acc[f] += __shfl_down(acc[f], off);
  }
  if (lane == 0) {
    #pragma unroll
    for (int f = 0; f < 8; ++f) {
      float v = acc[f] + eb[f];
      long idx = ((long)b * 1024 + f * 128 + band) * 128 + t;
      enc[idx] = v;
      encbf[idx] = f2bf(v);
    }
  }
}

// ---------------- ctx = sum over t of enc ----------------
__global__ void ctx_kernel(const float* __restrict__ enc, float* __restrict__ ctx) {
  int wid = threadIdx.x >> 6, lane = threadIdx.x & 63;
  int row = blockIdx.x * 4 + wid;  // [0, 4096)
  const float* r = enc + (long)row * 128;
  float s = r[lane] + r[lane + 64];
  #pragma unroll
  for (int off = 32; off; off >>= 1) s += __shfl_down(s, off);
  if (lane == 0) ctx[row] = s;
}

// ---------------- gemm: y(4,1024) = h(4,1024) @ w(1024,1024) + bias ----------------
__global__ void gemm4_kernel(const float* __restrict__ h, const float* __restrict__ w,
                             const float* __restrict__ bias, float* __restrict__ y) {
  __shared__ float hl[4096];
  __shared__ float red[8][4][32];
  for (int i = threadIdx.x; i < 4096; i += 256) hl[i] = h[i];
  __syncthreads();
  int jl = threadIdx.x & 31, kc = threadIdx.x >> 5;
  int j = blockIdx.x * 32 + jl;
  float a0 = 0, a1 = 0, a2 = 0, a3 = 0;
  const float* wp = w + (long)kc * 128 * 1024 + j;
  const float* h0 = hl + kc * 128;
  for (int k = 0; k < 128; ++k) {
    float wv = wp[(long)k * 1024];
    a0 += h0[k] * wv;
    a1 += h0[k + 1024] * wv;
    a2 += h0[k + 2048] * wv;
    a3 += h0[k + 3072] * wv;
  }
  red[kc][0][jl] = a0; red[kc][1][jl] = a1; red[kc][2][jl] = a2; red[kc][3][jl] = a3;
  __syncthreads();
  if (threadIdx.x < 128) {
    int b = threadIdx.x >> 5, j2 = threadIdx.x & 31;
    float s = 0;
    #pragma unroll
    for (int c = 0; c < 8; ++c) s += red[c][b][j2];
    y[b * 1024 + blockIdx.x * 32 + j2] = s + bias[blockIdx.x * 32 + j2];
  }
}

// ---------------- leaky + layernorm over last dim (1024) ----------------
__global__ void act_ln_kernel(const float* __restrict__ in, const float* __restrict__ g,
                              const float* __restrict__ be, float* __restrict__ out) {
  int b = blockIdx.x;
  __shared__ float buf[1024];
  __shared__ float rs[4], rq[4];
  const float* r = in + b * 1024;
  float s = 0, q = 0;
  #pragma unroll
  for (int i = 0; i < 4; ++i) {
    int j = threadIdx.x + i * 256;
    float v = leaky(r[j]);
    buf[j] = v; s += v; q += v * v;
  }
  #pragma unroll
  for (int off = 32; off; off >>= 1) { s += __shfl_down(s, off); q += __shfl_down(q, off); }
  int wid = threadIdx.x >> 6, lane = threadIdx.x & 63;
  if (lane == 0) { rs[wid] = s; rq[wid] = q; }
  __syncthreads();
  float S = rs[0] + rs[1] + rs[2] + rs[3];
  float Q = rq[0] + rq[1] + rq[2] + rq[3];
  float mean = S * (1.f / 1024.f);
  float var = Q * (1.f / 1024.f) - mean * mean;
  float rstd = rsqrtf(var + 1e-5f);
  #pragma unroll
  for (int i = 0; i < 4; ++i) {
    int j = threadIdx.x + i * 256;
    out[b * 1024 + j] = (buf[j] - mean) * rstd * g[j] + be[j];
  }
}

// ---------------- weight pack: f32 [Cout][Cin][7] -> bf16 [7][Cin/32][Cout][32] ----------------
__global__ void wcvt_kernel(const float* __restrict__ w, unsigned short* __restrict__ wpack,
                            int Cout, int Cin) {
  int n = Cout * Cin * 7;
  int nCib = Cin >> 5;
  for (int i = blockIdx.x * blockDim.x + threadIdx.x; i < n; i += gridDim.x * blockDim.x) {
    int co = i / (Cin * 7);
    int r  = i - co * (Cin * 7);
    int ci = r / 7;
    int k  = r - ci * 7;
    wpack[((long)(k * nCib + (ci >> 5)) * Cout + co) * 32 + (ci & 31)] = f2bf(w[i]);
  }
}

// ---------------- implicit-GEMM conv1d via MFMA bf16 ----------------
template<int UPS, int SPLITK>
__global__ __launch_bounds__(256, 2)
void conv_mfma(const unsigned short* __restrict__ act,
               const unsigned short* __restrict__ wpack,
               float* __restrict__ outp,
               int Cin, int Cout, int Tout) {
  constexpr int NC = (UPS == 1) ? 70 : 18;   // staged source columns per tile
  const int Tin = Tout / UPS;
  const int cpb = Cin / SPLITK;              // ci handled by this block
  const int ncib = cpb >> 5;
  const int nCibTot = Cin >> 5;
  const int nco = Cout >> 6, nt = Tout >> 6;

  int bid = blockIdx.x;
  const int sk = bid % SPLITK; bid /= SPLITK;
  const int tt = bid % nt;  bid /= nt;
  const int cot = bid % nco; bid /= nco;
  const int b = bid;
  const int t0 = tt << 6, co0 = cot << 6;
  const int ci0 = sk * cpb;

  extern __shared__ unsigned short lin[];    // [ncib][NC][40] (rows padded to 80B)

  const unsigned short* actb = act + ((long)b * Cin + ci0) * Tin;
  const int u_base = (UPS == 1) ? (t0 - 3) : ((t0 >> 2) - 1);
  const int total = cpb * NC;
  for (int i = threadIdx.x; i < total; i += 256) {
    int ci = i / NC, ul = i - ci * NC;
    int u = u_base + ul;
    unsigned short v = 0;
    if (u >= 0 && u < Tin) v = actb[(long)ci * Tin + u];
    lin[((ci >> 5) * NC + ul) * 40 + (ci & 31)] = v;
  }
  __syncthreads();

  const int lane = threadIdx.x & 63, w = threadIdx.x >> 6;
  const int m = lane & 15, g = lane >> 4;

  int boff[28];
  #pragma unroll
  for (int s = 0; s < 4; ++s) {
    #pragma unroll
    for (int k = 0; k < 7; ++k) {
      int row = (UPS == 1) ? (s * 16 + m + k)
                           : (s * 4 + ((m + k + 9) >> 2) - 2);
      boff[s * 7 + k] = row * 40 + g * 8;
    }
  }

  const long wlane = ((long)(co0 + w * 16 + m) * 4 + g) * 8;

  f32x4 acc[4];
  #pragma unroll
  for (int s = 0; s < 4; ++s) { acc[s][0] = 0.f; acc[s][1] = 0.f; acc[s][2] = 0.f; acc[s][3] = 0.f; }

  for (int cib = 0; cib < ncib; ++cib) {
    const unsigned short* lb = lin + cib * (NC * 40);
    const int cg = (ci0 >> 5) + cib;
    sh8 a[7];
    #pragma unroll
    for (int k = 0; k < 7; ++k)
      a[k] = *(const sh8*)(wpack + (long)(k * nCibTot + cg) * Cout * 32 + wlane);
    #pragma unroll
    for (int k = 0; k < 7; ++k) {
      #pragma unroll
      for (int s = 0; s < 4; ++s) {
        sh8 bfr = *(const sh8*)(lb + boff[s * 7 + k]);
        acc[s] = __builtin_amdgcn_mfma_f32_16x16x32_bf16(a[k], bfr, acc[s], 0, 0, 0);
      }
    }
  }

  float* op = outp + (((long)sk * 4 + b) * Cout + (co0 + w * 16 + g * 4)) * (long)Tout + t0 + m;
  #pragma unroll
  for (int r = 0; r < 4; ++r) {
    #pragma unroll
    for (int s = 0; s < 4; ++s)
      op[(long)r * Tout + s * 16] = acc[s][r];
  }
}

// ---------------- batchnorm stats over split-K partials -> scale/shift ----------------
__global__ void bn_stats(const float* __restrict__ p, const float* __restrict__ g,
                         const float* __restrict__ be, float* __restrict__ scale,
                         float* __restrict__ shift, int C, int T, int SK) {
  int co = blockIdx.x;
  long stride = (long)4 * C * T;
  float s = 0, q = 0;
  for (int b = 0; b < 4; ++b) {
    const float* r = p + ((long)b * C + co) * T;
    for (int t = threadIdx.x; t < T; t += blockDim.x) {
      float v = r[t];
      for (int k2 = 1; k2 < SK; ++k2) v += r[t + k2 * stride];
      s += v; q += v * v;
    }
  }
  #pragma unroll
  for (int off = 32; off; off >>= 1) { s += __shfl_down(s, off); q += __shfl_down(q, off); }
  __shared__ float rs[4], rq[4];
  int wid = threadIdx.x >> 6, lane = threadIdx.x & 63;
  if (lane == 0) { rs[wid] = s; rq[wid] = q; }
  __syncthreads();
  if (threadIdx.x == 0) {
    float S = rs[0] + rs[1] + rs[2] + rs[3];
    float Q = rq[0] + rq[1] + rq[2] + rq[3];
    float n = (float)(4 * T);
    float mean = S / n;
    float var = Q / n - mean * mean;
    float rstd = rsqrtf(var + 1e-5f);
    float sc = g[co] * rstd;
    scale[co] = sc;
    shift[co] = be[co] - mean * sc;
  }
}

// ---------------- apply bn + leaky, sum split-K partials, emit bf16 ----------------
__global__ void bn_apply(const float* __restrict__ p, const float* __restrict__ scale,
                         const float* __restrict__ shift, unsigned short* __restrict__ outbf,
                         int C, int T, int total, int SK) {
  int i = blockIdx.x * blockDim.x + threadIdx.x;
  if (i >= total) return;
  float v = p[i];
  for (int k = 1; k < SK; ++k) v += p[i + (long)k * total];
  int co = (i / T) % C;
  outbf[i] = f2bf(leaky(v * scale[co] + shift[co]));
}

// ---------------- final conv: Cin=64, Cout=1, UPS=4 -> phase-decomposed 3-tap conv ----------------
// in: bf16 (4,64,8192). out: f32 (4,32768). grid (128,4) x 256 thr.
// Per phase p of t=4u+p, taps collapse to 3 source taps d in {-1,0,+1} with
// pre-summed weights W[p][d]. LDS window [64ci][66u] zero-filled reproduces pad-3.
__global__ __launch_bounds__(256)
void conv5_kernel(const unsigned short* __restrict__ in, const float* __restrict__ wgt,
                  const float* __restrict__ bias, float* __restrict__ out, int Tout) {
  __shared__ unsigned short sv[64 * 66];   // [ci][uu], stride 66 (2-way bank alias: free)
  __shared__ float wph[64 * 13];           // [ci][p*3+d], stride 13

  const int b = blockIdx.y;
  const int u0 = blockIdx.x * 64;
  const int Tin = Tout >> 2;
  const int tid = threadIdx.x;

  // effective 3-tap weights: thread (ci,p)
  {
    int ci = tid >> 2, p = tid & 3;
    float s0 = 0, s1 = 0, s2 = 0;
    #pragma unroll
    for (int k = 0; k < 7; ++k) {
      int d = (p - 3 + k + 4) >> 2;   // 0,1,2 (staged offset)
      float wv = wgt[ci * 7 + k];
      if (d == 0) s0 += wv; else if (d == 1) s1 += wv; else s2 += wv;
    }
    wph[ci * 13 + p * 3 + 0] = s0;
    wph[ci * 13 + p * 3 + 1] = s1;
    wph[ci * 13 + p * 3 + 2] = s2;
  }

  // stage input window: uu in [0,66) <-> u = u0 - 1 + uu; OOB -> 0 (== conv zero-pad)
  const unsigned short* inb = in + (long)b * 64 * Tin;
  for (int i = tid; i < 64 * 66; i += 256) {
    int ci = i / 66, uu = i - ci * 66;
    int u = u0 - 1 + uu;
    unsigned short v = 0;
    if (u >= 0 && u < Tin) v = inb[(long)ci * Tin + u];
    sv[ci * 66 + uu] = v;
  }
  __syncthreads();

  const int ul = tid >> 2;       // u within tile, 0..63
  const int chunk = tid & 3;     // ci chunk (16 each)
  float a0 = 0, a1 = 0, a2 = 0, a3 = 0;
  #pragma unroll
  for (int cc = 0; cc < 16; ++cc) {
    int ci = chunk * 16 + cc;
    float v0 = bf2f(sv[ci * 66 + ul]);
    float v1 = bf2f(sv[ci * 66 + ul + 1]);
    float v2 = bf2f(sv[ci * 66 + ul + 2]);
    const float* wp = wph + ci * 13;
    a0 += v0 * wp[0] + v1 * wp[1];               // p=0: d2 sum is 0
    a1 += v0 * wp[3] + v1 * wp[4] + v2 * wp[5];  // p=1
    a2 += v0 * wp[6] + v1 * wp[7] + v2 * wp[8];  // p=2
    a3 += v1 * wp[10] + v2 * wp[11];             // p=3: d0 sum is 0
  }
  #pragma unroll
  for (int msk = 1; msk <= 2; msk <<= 1) {
    a0 += __shfl_xor(a0, msk);
    a1 += __shfl_xor(a1, msk);
    a2 += __shfl_xor(a2, msk);
    a3 += __shfl_xor(a3, msk);
  }
  if (chunk == 0) {
    float bv = bias[0];
    float4 r = make_float4(a0 + bv, a1 + bv, a2 + bv, a3 + bv);
    *(float4*)(out + (long)b * Tout + (long)(u0 + ul) * 4) = r;
  }
}

extern "C" void kernel_launch(void* const* d_in, const int* in_sizes, int n_in,
                              void* d_out, int out_size, void* d_ws, size_t ws_size,
                              hipStream_t stream) {
  const float* x     = (const float*)d_in[0];
  // d_in[1] = atoms: dead code (sparse_code result unused by outputs)
  const float* ew    = (const float*)d_in[2];
  const float* eb    = (const float*)d_in[3];
  const float* w1    = (const float*)d_in[4];
  const float* b1    = (const float*)d_in[5];
  const float* g1    = (const float*)d_in[6];
  const float* be1   = (const float*)d_in[7];
  const float* w2    = (const float*)d_in[8];
  const float* b2    = (const float*)d_in[9];
  const float* g2    = (const float*)d_in[10];
  const float* be2   = (const float*)d_in[11];
  const float* w3    = (const float*)d_in[12];
  const float* b3    = (const float*)d_in[13];
  const float* up_w1 = (const float*)d_in[14];
  const float* up_b1 = (const float*)d_in[15];
  const float* bn_g1 = (const float*)d_in[16];
  const float* bn_b1 = (const float*)d_in[17];
  const float* up_w2 = (const float*)d_in[18];
  const float* up_b2 = (const float*)d_in[19];
  const float* bn_g2 = (const float*)d_in[20];
  const float* bn_b2 = (const float*)d_in[21];
  const float* up_w3 = (const float*)d_in[22];
  const float* up_b3 = (const float*)d_in[23];
  const float* bn_g3 = (const float*)d_in[24];
  const float* bn_b3 = (const float*)d_in[25];
  const float* up_w4 = (const float*)d_in[26];
  const float* up_b4 = (const float*)d_in[27];
  const float* bn_g4 = (const float*)d_in[28];
  const float* bn_b4 = (const float*)d_in[29];
  const float* up_w5 = (const float*)d_in[30];
  const float* up_b5 = (const float*)d_in[31];

  float* out = (float*)d_out;          // [0,131072) = y, [131072,135168) = ctx_out

  float* ws = (float*)d_ws;
  float* enc   = ws;                          // 524288 f32
  float* ctxb  = enc + 524288;                // 4096
  float* t1    = ctxb + 4096;                 // 4096
  float* t2    = t1 + 4096;                   // 4096
  float* scale = t2 + 4096;                   // 512
  float* shift = scale + 512;                 // 512
  float* pbuf  = shift + 512;                 // 2097152 f32 (max over stages, incl. split-K)
  unsigned short* encbf = (unsigned short*)(pbuf + 2097152);  // 524288
  unsigned short* actA  = encbf + 524288;     // 2097152
  unsigned short* actB  = actA + 2097152;     // 1048576
  unsigned short* wbuf  = actB + 1048576;     // 3670016 (max weight pack)

  embed_kernel<<<16384, 256, 0, stream>>>(x, ew, eb, enc, encbf);

  // ctx path (f32 throughout)
  ctx_kernel<<<1024, 256, 0, stream>>>(enc, ctxb);
  gemm4_kernel<<<32, 256, 0, stream>>>(ctxb, w1, b1, t1);
  act_ln_kernel<<<4, 256, 0, stream>>>(t1, g1, be1, t2);
  gemm4_kernel<<<32, 256, 0, stream>>>(t2, w2, b2, t1);
  act_ln_kernel<<<4, 256, 0, stream>>>(t1, g2, be2, t2);
  gemm4_kernel<<<32, 256, 0, stream>>>(t2, w3, b3, out + 131072);

  // ---- conv stage 1: (4,1024,128) -> (4,512,128), UPS=1, split-K=4 ----
  wcvt_kernel<<<2048, 256, 0, stream>>>(up_w1, wbuf, 512, 1024);
  conv_mfma<1, 4><<<256, 256, 44800, stream>>>(encbf, wbuf, pbuf, 1024, 512, 128);
  bn_stats<<<512, 256, 0, stream>>>(pbuf, bn_g1, bn_b1, scale, shift, 512, 128, 4);
  bn_apply<<<1024, 256, 0, stream>>>(pbuf, scale, shift, actB, 512, 128, 262144, 4);

  // ---- conv stage 2: (4,512,128) -up4-> (4,256,512), split-K=2 ----
  wcvt_kernel<<<2048, 256, 0, stream>>>(up_w2, wbuf, 256, 512);
  conv_mfma<4, 2><<<256, 256, 11520, stream>>>(actB, wbuf, pbuf, 512, 256, 512);
  bn_stats<<<256, 256, 0, stream>>>(pbuf, bn_g2, bn_b2, scale, shift, 256, 512, 2);
  bn_apply<<<2048, 256, 0, stream>>>(pbuf, scale, shift, actA, 256, 512, 524288, 2);

  // ---- conv stage 3: (4,256,512) -up4-> (4,128,2048) ----
  wcvt_kernel<<<2048, 256, 0, stream>>>(up_w3, wbuf, 128, 256);
  conv_mfma<4, 1><<<256, 256, 11520, stream>>>(actA, wbuf, pbuf, 256, 128, 2048);
  bn_stats<<<128, 256, 0, stream>>>(pbuf, bn_g3, bn_b3, scale, shift, 128, 2048, 1);
  bn_apply<<<4096, 256, 0, stream>>>(pbuf, scale, shift, actB, 128, 2048, 1048576, 1);

  // ---- conv stage 4: (4,128,2048) -up4-> (4,64,8192) ----
  wcvt_kernel<<<2048, 256, 0, stream>>>(up_w4, wbuf, 64, 128);
  conv_mfma<4, 1><<<512, 256, 5760, stream>>>(actB, wbuf, pbuf, 128, 64, 8192);
  bn_stats<<<64, 256, 0, stream>>>(pbuf, bn_g4, bn_b4, scale, shift, 64, 8192, 1);
  bn_apply<<<8192, 256, 0, stream>>>(pbuf, scale, shift, actA, 64, 8192, 2097152, 1);

  // ---- conv stage 5: (4,64,8192) -up4-> (4,1,32768), phase-decomposed ----
  conv5_kernel<<<dim3(128, 4), 256, 0, stream>>>(actA, up_w5, up_b5, out, 32768);
}

// Round 4
// 187.466 us; speedup vs baseline: 6.1184x; 1.4724x over previous
//
#include <hip/hip_runtime.h>
#include <hip/hip_bf16.h>

using sh8   = __attribute__((ext_vector_type(8))) short;
using f32x4 = __attribute__((ext_vector_type(4))) float;

#define DEV __device__ __forceinline__

DEV float leaky(float x) { return x >= 0.f ? x : 0.2f * x; }

DEV unsigned short f2bf(float f) {  // round-to-nearest-even f32 -> bf16 bits
  unsigned u = __float_as_uint(f);
  u += 0x7FFF + ((u >> 16) & 1);
  return (unsigned short)(u >> 16);
}
DEV float bf2f(unsigned short b) { return __uint_as_float(((unsigned)b) << 16); }

// ---------------- embed v2: LDS-staged rows, SGPR-broadcast weights ----------------
// x: (4,128,128,257) f32. Block = 64 consecutive rows (one (b,band), t-half).
// Writes encbf (bf16, transposed) and ctx 2-partial sums (deterministic).
__global__ __launch_bounds__(256)
void embed_kernel(const float* __restrict__ x, const float* __restrict__ ew,
                  const float* __restrict__ eb, unsigned short* __restrict__ encbf,
                  float* __restrict__ part) {
  __shared__ float smem[16448];           // 64 rows x 257 f32, flat
  const int row0 = blockIdx.x * 64;
  const int b = row0 >> 14, band = (row0 >> 7) & 127, t0 = row0 & 127;

  // stage: 4112 float4, fully coalesced
  const float4* src = (const float4*)(x + (long)row0 * 257);
  float4* dst4 = (float4*)smem;
  for (int i = threadIdx.x; i < 4112; i += 256) dst4[i] = src[i];
  __syncthreads();

  const int w = threadIdx.x >> 6, lane = threadIdx.x & 63;
  float acc[8] = {0, 0, 0, 0, 0, 0, 0, 0};
  const int cnt = (w == 3) ? 65 : 64;     // wave 3 also takes p=256
  const float* xr = smem + lane * 257 + w * 64;   // bank (lane + p) % 32: 2-way, free
  for (int j = 0; j < cnt; ++j) {
    int p = __builtin_amdgcn_readfirstlane(w * 64 + j);  // wave-uniform -> s_load ew
    float xv = xr[j];
    const float4* wp = (const float4*)(ew + p * 8);
    float4 wa = wp[0], wb = wp[1];
    acc[0] += xv * wa.x; acc[1] += xv * wa.y; acc[2] += xv * wa.z; acc[3] += xv * wa.w;
    acc[4] += xv * wb.x; acc[5] += xv * wb.y; acc[6] += xv * wb.z; acc[7] += xv * wb.w;
  }
  __syncthreads();                         // all reads of smem done
  #pragma unroll
  for (int f = 0; f < 8; ++f) smem[w * 512 + lane * 8 + f] = acc[f];
  __syncthreads();

  // wave w finalizes f = {2w, 2w+1}; lane = t within half-tile
  const int f0 = w * 2;
  float e0 = eb[f0], e1 = eb[f0 + 1];
  #pragma unroll
  for (int ww = 0; ww < 4; ++ww) {
    e0 += smem[ww * 512 + lane * 8 + f0];
    e1 += smem[ww * 512 + lane * 8 + f0 + 1];
  }
  long o0 = ((long)b * 1024 + f0 * 128 + band) * 128 + t0 + lane;
  encbf[o0] = f2bf(e0);
  encbf[o0 + 16384] = f2bf(e1);
  // ctx partial: sum over the 64 t's in this tile
  float s0 = e0, s1 = e1;
  #pragma unroll
  for (int off = 32; off; off >>= 1) { s0 += __shfl_down(s0, off); s1 += __shfl_down(s1, off); }
  if (lane == 0) {
    int half = t0 >> 6;
    part[((b * 1024 + f0 * 128 + band) << 1) + half] = s0;
    part[((b * 1024 + (f0 + 1) * 128 + band) << 1) + half] = s1;
  }
}

// ---------------- split-K gemm: partial y = h(4,1024) @ w[k-chunk] ----------------
// grid (32 jb, 8 kc) x 256. SUM2: h is the 2-partial ctx buffer.
template<int SUM2>
__global__ void gemm_p(const float* __restrict__ h, const float* __restrict__ w,
                       float* __restrict__ gpart) {
  __shared__ float hl[4][128];
  __shared__ float red[8][4][32];
  const int kc = blockIdx.y, jb = blockIdx.x, k0 = kc * 128;
  for (int i = threadIdx.x; i < 512; i += 256) {
    int bb = i >> 7, kk = i & 127;
    float v;
    if (SUM2) {
      int base = ((bb << 10) + k0 + kk) << 1;
      v = h[base] + h[base + 1];
    } else {
      v = h[(bb << 10) + k0 + kk];
    }
    hl[bb][kk] = v;
  }
  __syncthreads();
  const int jl = threadIdx.x & 31, kq = threadIdx.x >> 5;   // 8 k-subchunks of 16
  const int j = jb * 32 + jl;
  float a0 = 0, a1 = 0, a2 = 0, a3 = 0;
  const float* wp = w + (long)(k0 + kq * 16) * 1024 + j;
  #pragma unroll
  for (int k = 0; k < 16; ++k) {
    float wv = wp[(long)k * 1024];
    a0 += hl[0][kq * 16 + k] * wv;
    a1 += hl[1][kq * 16 + k] * wv;
    a2 += hl[2][kq * 16 + k] * wv;
    a3 += hl[3][kq * 16 + k] * wv;
  }
  red[kq][0][jl] = a0; red[kq][1][jl] = a1; red[kq][2][jl] = a2; red[kq][3][jl] = a3;
  __syncthreads();
  if (threadIdx.x < 128) {
    int bb = threadIdx.x >> 5, j2 = threadIdx.x & 31;
    float s = 0;
    #pragma unroll
    for (int q = 0; q < 8; ++q) s += red[q][bb][j2];
    gpart[((long)kc * 4 + bb) * 1024 + jb * 32 + j2] = s;
  }
}

// ---------------- sum split-K partials + bias + leaky + layernorm ----------------
__global__ void lnsum_kernel(const float* __restrict__ gpart, const float* __restrict__ bias,
                             const float* __restrict__ g, const float* __restrict__ be,
                             float* __restrict__ out) {
  int b = blockIdx.x;
  __shared__ float buf[1024];
  __shared__ float rs[4], rq[4];
  float s = 0, q = 0;
  #pragma unroll
  for (int i = 0; i < 4; ++i) {
    int j = threadIdx.x + i * 256;
    float v = bias[j];
    #pragma unroll
    for (int kc = 0; kc < 8; ++kc) v += gpart[((long)kc * 4 + b) * 1024 + j];
    v = leaky(v);
    buf[j] = v; s += v; q += v * v;
  }
  #pragma unroll
  for (int off = 32; off; off >>= 1) { s += __shfl_down(s, off); q += __shfl_down(q, off); }
  int wid = threadIdx.x >> 6, lane = threadIdx.x & 63;
  if (lane == 0) { rs[wid] = s; rq[wid] = q; }
  __syncthreads();
  float S = rs[0] + rs[1] + rs[2] + rs[3];
  float Q = rq[0] + rq[1] + rq[2] + rq[3];
  float mean = S * (1.f / 1024.f);
  float var = Q * (1.f / 1024.f) - mean * mean;
  float rstd = rsqrtf(var + 1e-5f);
  #pragma unroll
  for (int i = 0; i < 4; ++i) {
    int j = threadIdx.x + i * 256;
    out[b * 1024 + j] = (buf[j] - mean) * rstd * g[j] + be[j];
  }
}

// ---------------- final: ctx_out = sum partials + bias ----------------
__global__ void fin_kernel(const float* __restrict__ gpart, const float* __restrict__ bias,
                           float* __restrict__ out) {
  int i = blockIdx.x * 256 + threadIdx.x;   // 4096
  int b = i >> 10, j = i & 1023;
  float v = bias[j];
  #pragma unroll
  for (int kc = 0; kc < 8; ++kc) v += gpart[((long)kc * 4 + b) * 1024 + j];
  out[i] = v;
}

// ---------------- pack all 4 conv weights: f32 [Cout][Cin][7] -> bf16 [7][Cin/32][Cout][32] ----------------
DEV void pack_one(const float* __restrict__ w, unsigned short* __restrict__ wp,
                  int Cout, int Cin, int tid, int nthr) {
  int n = Cout * Cin * 7;
  int nCib = Cin >> 5;
  for (int i = tid; i < n; i += nthr) {
    int co = i / (Cin * 7);
    int r  = i - co * (Cin * 7);
    int ci = r / 7;
    int k  = r - ci * 7;
    wp[((long)(k * nCib + (ci >> 5)) * Cout + co) * 32 + (ci & 31)] = f2bf(w[i]);
  }
}
__global__ void wcvt_all(const float* __restrict__ w1, const float* __restrict__ w2,
                         const float* __restrict__ w3, const float* __restrict__ w4,
                         unsigned short* __restrict__ wbuf) {
  int tid = blockIdx.x * blockDim.x + threadIdx.x;
  int nthr = gridDim.x * blockDim.x;
  pack_one(w1, wbuf,           512, 1024, tid, nthr);
  pack_one(w2, wbuf + 3670016, 256,  512, tid, nthr);
  pack_one(w3, wbuf + 4587520, 128,  256, tid, nthr);
  pack_one(w4, wbuf + 4816896,  64,  128, tid, nthr);
}

// ---------------- implicit-GEMM conv1d via MFMA bf16 ----------------
template<int UPS, int SPLITK>
__global__ __launch_bounds__(256, 2)
void conv_mfma(const unsigned short* __restrict__ act,
               const unsigned short* __restrict__ wpack,
               float* __restrict__ outp,
               int Cin, int Cout, int Tout) {
  constexpr int NC = (UPS == 1) ? 70 : 18;
  const int Tin = Tout / UPS;
  const int cpb = Cin / SPLITK;
  const int ncib = cpb >> 5;
  const int nCibTot = Cin >> 5;
  const int nco = Cout >> 6, nt = Tout >> 6;

  int bid = blockIdx.x;
  const int sk = bid % SPLITK; bid /= SPLITK;
  const int tt = bid % nt;  bid /= nt;
  const int cot = bid % nco; bid /= nco;
  const int b = bid;
  const int t0 = tt << 6, co0 = cot << 6;
  const int ci0 = sk * cpb;

  extern __shared__ unsigned short lin[];    // [ncib][NC][40]

  const unsigned short* actb = act + ((long)b * Cin + ci0) * Tin;
  const int u_base = (UPS == 1) ? (t0 - 3) : ((t0 >> 2) - 1);
  const int total = cpb * NC;
  for (int i = threadIdx.x; i < total; i += 256) {
    int ci = i / NC, ul = i - ci * NC;
    int u = u_base + ul;
    unsigned short v = 0;
    if (u >= 0 && u < Tin) v = actb[(long)ci * Tin + u];
    lin[((ci >> 5) * NC + ul) * 40 + (ci & 31)] = v;
  }
  __syncthreads();

  const int lane = threadIdx.x & 63, w = threadIdx.x >> 6;
  const int m = lane & 15, g = lane >> 4;

  int boff[28];
  #pragma unroll
  for (int s = 0; s < 4; ++s) {
    #pragma unroll
    for (int k = 0; k < 7; ++k) {
      int row = (UPS == 1) ? (s * 16 + m + k)
                           : (s * 4 + ((m + k + 9) >> 2) - 2);
      boff[s * 7 + k] = row * 40 + g * 8;
    }
  }

  const long wlane = ((long)(co0 + w * 16 + m) * 4 + g) * 8;

  f32x4 acc[4];
  #pragma unroll
  for (int s = 0; s < 4; ++s) { acc[s][0] = 0.f; acc[s][1] = 0.f; acc[s][2] = 0.f; acc[s][3] = 0.f; }

  for (int cib = 0; cib < ncib; ++cib) {
    const unsigned short* lb = lin + cib * (NC * 40);
    const int cg = (ci0 >> 5) + cib;
    sh8 a[7];
    #pragma unroll
    for (int k = 0; k < 7; ++k)
      a[k] = *(const sh8*)(wpack + (long)(k * nCibTot + cg) * Cout * 32 + wlane);
    #pragma unroll
    for (int k = 0; k < 7; ++k) {
      #pragma unroll
      for (int s = 0; s < 4; ++s) {
        sh8 bfr = *(const sh8*)(lb + boff[s * 7 + k]);
        acc[s] = __builtin_amdgcn_mfma_f32_16x16x32_bf16(a[k], bfr, acc[s], 0, 0, 0);
      }
    }
  }

  float* op = outp + (((long)sk * 4 + b) * Cout + (co0 + w * 16 + g * 4)) * (long)Tout + t0 + m;
  #pragma unroll
  for (int r = 0; r < 4; ++r) {
    #pragma unroll
    for (int s = 0; s < 4; ++s)
      op[(long)r * Tout + s * 16] = acc[s][r];
  }
}

// ---------------- bn partial stats: grid (C, 4b) ----------------
__global__ void bnsum_kernel(const float* __restrict__ p, float* __restrict__ sp,
                             int C, int T, int SK) {
  int c = blockIdx.x, b = blockIdx.y;
  long stride = (long)4 * C * T;
  const float* r = p + ((long)b * C + c) * T;
  float s = 0, q = 0;
  for (int t = threadIdx.x; t < T; t += 256) {
    float v = r[t];
    for (int k = 1; k < SK; ++k) v += r[t + k * stride];
    s += v; q += v * v;
  }
  #pragma unroll
  for (int off = 32; off; off >>= 1) { s += __shfl_down(s, off); q += __shfl_down(q, off); }
  __shared__ float rs[4], rq[4];
  int wid = threadIdx.x >> 6, lane = threadIdx.x & 63;
  if (lane == 0) { rs[wid] = s; rq[wid] = q; }
  __syncthreads();
  if (threadIdx.x == 0) {
    sp[c * 4 + b] = rs[0] + rs[1] + rs[2] + rs[3];
    sp[C * 4 + c * 4 + b] = rq[0] + rq[1] + rq[2] + rq[3];
  }
}

// ---------------- bn finalize + leaky + sum split-K, emit bf16 ----------------
__global__ void bnapply_kernel(const float* __restrict__ p, const float* __restrict__ sp,
                               const float* __restrict__ g, const float* __restrict__ be,
                               unsigned short* __restrict__ obf,
                               int C, int tshift, int total, int SK) {
  int i = blockIdx.x * 256 + threadIdx.x;
  if (i >= total) return;
  float v = p[i];
  for (int k = 1; k < SK; ++k) v += p[i + (long)k * total];
  int c = (i >> tshift) & (C - 1);
  float s = sp[c * 4] + sp[c * 4 + 1] + sp[c * 4 + 2] + sp[c * 4 + 3];
  float q = sp[C * 4 + c * 4] + sp[C * 4 + c * 4 + 1] + sp[C * 4 + c * 4 + 2] + sp[C * 4 + c * 4 + 3];
  float n = (float)(4 << tshift);
  float mean = s / n;
  float var = q / n - mean * mean;
  float sc = g[c] * rsqrtf(var + 1e-5f);
  float sh = be[c] - mean * sc;
  obf[i] = f2bf(leaky(v * sc + sh));
}

// ---------------- final conv: phase-decomposed 3-tap ----------------
__global__ __launch_bounds__(256)
void conv5_kernel(const unsigned short* __restrict__ in, const float* __restrict__ wgt,
                  const float* __restrict__ bias, float* __restrict__ out, int Tout) {
  __shared__ unsigned short sv[64 * 66];
  __shared__ float wph[64 * 13];

  const int b = blockIdx.y;
  const int u0 = blockIdx.x * 64;
  const int Tin = Tout >> 2;
  const int tid = threadIdx.x;

  {
    int ci = tid >> 2, pp = tid & 3;
    float s0 = 0, s1 = 0, s2 = 0;
    #pragma unroll
    for (int k = 0; k < 7; ++k) {
      int d = (pp - 3 + k + 4) >> 2;
      float wv = wgt[ci * 7 + k];
      if (d == 0) s0 += wv; else if (d == 1) s1 += wv; else s2 += wv;
    }
    wph[ci * 13 + pp * 3 + 0] = s0;
    wph[ci * 13 + pp * 3 + 1] = s1;
    wph[ci * 13 + pp * 3 + 2] = s2;
  }

  const unsigned short* inb = in + (long)b * 64 * Tin;
  for (int i = tid; i < 64 * 66; i += 256) {
    int ci = i / 66, uu = i - ci * 66;
    int u = u0 - 1 + uu;
    unsigned short v = 0;
    if (u >= 0 && u < Tin) v = inb[(long)ci * Tin + u];
    sv[ci * 66 + uu] = v;
  }
  __syncthreads();

  const int ul = tid >> 2;
  const int chunk = tid & 3;
  float a0 = 0, a1 = 0, a2 = 0, a3 = 0;
  #pragma unroll
  for (int cc = 0; cc < 16; ++cc) {
    int ci = chunk * 16 + cc;
    float v0 = bf2f(sv[ci * 66 + ul]);
    float v1 = bf2f(sv[ci * 66 + ul + 1]);
    float v2 = bf2f(sv[ci * 66 + ul + 2]);
    const float* wp = wph + ci * 13;
    a0 += v0 * wp[0] + v1 * wp[1];
    a1 += v0 * wp[3] + v1 * wp[4] + v2 * wp[5];
    a2 += v0 * wp[6] + v1 * wp[7] + v2 * wp[8];
    a3 += v1 * wp[10] + v2 * wp[11];
  }
  #pragma unroll
  for (int msk = 1; msk <= 2; msk <<= 1) {
    a0 += __shfl_xor(a0, msk);
    a1 += __shfl_xor(a1, msk);
    a2 += __shfl_xor(a2, msk);
    a3 += __shfl_xor(a3, msk);
  }
  if (chunk == 0) {
    float bv = bias[0];
    float4 r = make_float4(a0 + bv, a1 + bv, a2 + bv, a3 + bv);
    *(float4*)(out + (long)b * Tout + (long)(u0 + ul) * 4) = r;
  }
}

extern "C" void kernel_launch(void* const* d_in, const int* in_sizes, int n_in,
                              void* d_out, int out_size, void* d_ws, size_t ws_size,
                              hipStream_t stream) {
  const float* x     = (const float*)d_in[0];
  // d_in[1] = atoms: dead (sparse_code result unused by outputs)
  const float* ew    = (const float*)d_in[2];
  const float* eb    = (const float*)d_in[3];
  const float* w1    = (const float*)d_in[4];
  const float* b1    = (const float*)d_in[5];
  const float* g1    = (const float*)d_in[6];
  const float* be1   = (const float*)d_in[7];
  const float* w2    = (const float*)d_in[8];
  const float* b2    = (const float*)d_in[9];
  const float* g2    = (const float*)d_in[10];
  const float* be2   = (const float*)d_in[11];
  const float* w3    = (const float*)d_in[12];
  const float* b3    = (const float*)d_in[13];
  const float* up_w1 = (const float*)d_in[14];
  const float* up_b1 = (const float*)d_in[15];
  const float* bn_g1 = (const float*)d_in[16];
  const float* bn_b1 = (const float*)d_in[17];
  const float* up_w2 = (const float*)d_in[18];
  const float* up_b2 = (const float*)d_in[19];
  const float* bn_g2 = (const float*)d_in[20];
  const float* bn_b2 = (const float*)d_in[21];
  const float* up_w3 = (const float*)d_in[22];
  const float* up_b3 = (const float*)d_in[23];
  const float* bn_g3 = (const float*)d_in[24];
  const float* bn_b3 = (const float*)d_in[25];
  const float* up_w4 = (const float*)d_in[26];
  const float* up_b4 = (const float*)d_in[27];
  const float* bn_g4 = (const float*)d_in[28];
  const float* bn_b4 = (const float*)d_in[29];
  const float* up_w5 = (const float*)d_in[30];
  const float* up_b5 = (const float*)d_in[31];

  float* out = (float*)d_out;              // [0,131072) = y, [131072,135168) = ctx_out

  float* ws = (float*)d_ws;
  float* part   = ws;                      // 8192
  float* gpart  = part + 8192;             // 32768
  float* t2     = gpart + 32768;           // 4096
  float* statsp = t2 + 4096;               // 4096
  float* pbuf   = statsp + 4096;           // 2097152
  unsigned short* encbf = (unsigned short*)(pbuf + 2097152);  // 524288 u16
  unsigned short* o1 = encbf + 524288;     // 262144 u16
  unsigned short* o2 = o1 + 262144;        // 524288 u16
  unsigned short* o3 = o2 + 524288;        // 1048576 u16
  unsigned short* o4 = o3 + 1048576;       // 2097152 u16
  unsigned short* wbuf = o4 + 2097152;     // 4874240 u16

  // embed (+ fused ctx partials)
  embed_kernel<<<1024, 256, 0, stream>>>(x, ew, eb, encbf, part);

  // ctx MLP (split-K gemms, deterministic partial sums)
  gemm_p<1><<<dim3(32, 8), 256, 0, stream>>>(part, w1, gpart);
  lnsum_kernel<<<4, 256, 0, stream>>>(gpart, b1, g1, be1, t2);
  gemm_p<0><<<dim3(32, 8), 256, 0, stream>>>(t2, w2, gpart);
  lnsum_kernel<<<4, 256, 0, stream>>>(gpart, b2, g2, be2, t2);
  gemm_p<0><<<dim3(32, 8), 256, 0, stream>>>(t2, w3, gpart);
  fin_kernel<<<16, 256, 0, stream>>>(gpart, b3, out + 131072);

  // pack all conv weights in one launch
  wcvt_all<<<2048, 256, 0, stream>>>(up_w1, up_w2, up_w3, up_w4, wbuf);

  // ---- stage 1: (4,1024,128) -> (4,512,128), UPS=1, SK=8 ----
  conv_mfma<1, 8><<<512, 256, 22400, stream>>>(encbf, wbuf, pbuf, 1024, 512, 128);
  bnsum_kernel<<<dim3(512, 4), 256, 0, stream>>>(pbuf, statsp, 512, 128, 8);
  bnapply_kernel<<<1024, 256, 0, stream>>>(pbuf, statsp, bn_g1, bn_b1, o1, 512, 7, 262144, 8);

  // ---- stage 2: -up4-> (4,256,512), SK=4 ----
  conv_mfma<4, 4><<<512, 256, 5760, stream>>>(o1, wbuf + 3670016, pbuf, 512, 256, 512);
  bnsum_kernel<<<dim3(256, 4), 256, 0, stream>>>(pbuf, statsp, 256, 512, 4);
  bnapply_kernel<<<2048, 256, 0, stream>>>(pbuf, statsp, bn_g2, bn_b2, o2, 256, 9, 524288, 4);

  // ---- stage 3: -up4-> (4,128,2048), SK=2 ----
  conv_mfma<4, 2><<<512, 256, 5760, stream>>>(o2, wbuf + 4587520, pbuf, 256, 128, 2048);
  bnsum_kernel<<<dim3(128, 4), 256, 0, stream>>>(pbuf, statsp, 128, 2048, 2);
  bnapply_kernel<<<4096, 256, 0, stream>>>(pbuf, statsp, bn_g3, bn_b3, o3, 128, 11, 1048576, 2);

  // ---- stage 4: -up4-> (4,64,8192), SK=1 ----
  conv_mfma<4, 1><<<512, 256, 5760, stream>>>(o3, wbuf + 4816896, pbuf, 128, 64, 8192);
  bnsum_kernel<<<dim3(64, 4), 256, 0, stream>>>(pbuf, statsp, 64, 8192, 1);
  bnapply_kernel<<<8192, 256, 0, stream>>>(pbuf, statsp, bn_g4, bn_b4, o4, 64, 13, 2097152, 1);

  // ---- stage 5: -up4-> (4,1,32768), phase-decomposed ----
  conv5_kernel<<<dim3(128, 4), 256, 0, stream>>>(o4, up_w5, up_b5, out, 32768);
}

// Round 5
// 177.140 us; speedup vs baseline: 6.4751x; 1.0583x over previous
//
#include <hip/hip_runtime.h>
#include <hip/hip_bf16.h>

using sh8   = __attribute__((ext_vector_type(8))) short;
using f32x4 = __attribute__((ext_vector_type(4))) float;

#define DEV __device__ __forceinline__

DEV float leaky(float x) { return x >= 0.f ? x : 0.2f * x; }

DEV unsigned short f2bf(float f) {  // round-to-nearest-even f32 -> bf16 bits
  unsigned u = __float_as_uint(f);
  u += 0x7FFF + ((u >> 16) & 1);
  return (unsigned short)(u >> 16);
}
DEV float bf2f(unsigned short b) { return __uint_as_float(((unsigned)b) << 16); }

// ---------------- embed v3: MFMA GEMM (M=rows, K=257, N=8 padded 16) ----------------
// Block = one (b,band) group = 128 rows. 4 waves x 2 tiles of 16 rows.
// Writes encbf (bf16 transposed) and FINAL ctx (fused column reduce).
__global__ __launch_bounds__(256)
void embed_mfma(const float* __restrict__ x, const float* __restrict__ ew,
                const float* __restrict__ eb, unsigned short* __restrict__ encbf,
                float* __restrict__ ctx) {
  __shared__ unsigned short W16[257 * 16];   // [p][f], f>=8 zeroed
  __shared__ float ctxred[4][8];
  const int tid = threadIdx.x;

  for (int i = tid; i < 257 * 16; i += 256) {
    int p = i >> 4, f = i & 15;
    W16[i] = (f < 8) ? f2bf(ew[p * 8 + f]) : (unsigned short)0;
  }
  __syncthreads();

  const int w = tid >> 6, lane = tid & 63;
  const int m = lane & 15, g = lane >> 4;   // m: A-row / D-col(f); g: k-group / D-row-group

  // B-fragments (W), hoisted once per wave: breg[kk][j] = W[kk*32+g*8+j][m]
  sh8 breg[8];
  #pragma unroll
  for (int kk = 0; kk < 8; ++kk) {
    #pragma unroll
    for (int j = 0; j < 8; ++j)
      breg[kk][j] = (short)W16[(kk * 32 + g * 8 + j) * 16 + m];
  }
  const float w256 = bf2f(W16[256 * 16 + m]);
  const float ebf = (m < 8) ? eb[m] : 0.f;

  const int bid = blockIdx.x;               // 512 groups
  const long rowbase = (long)bid * 128;
  const int b = bid >> 7, band = bid & 127;

  float ctx_acc = 0.f;
  #pragma unroll
  for (int s = 0; s < 2; ++s) {
    const int t0 = w * 32 + s * 16;
    const float* xp = x + (rowbase + t0 + m) * 257;
    f32x4 acc = {0.f, 0.f, 0.f, 0.f};
    #pragma unroll
    for (int kk = 0; kk < 8; ++kk) {
      const float* xk = xp + kk * 32 + g * 8;
      sh8 afr;
      #pragma unroll
      for (int j = 0; j < 8; ++j) afr[j] = (short)f2bf(xk[j]);
      acc = __builtin_amdgcn_mfma_f32_16x16x32_bf16(afr, breg[kk], acc, 0, 0, 0);
    }
    // k=256 rank-1 + bias; lanes with m>=8 produce exact 0 (W cols zero-padded)
    const float* xq = x + (rowbase + t0 + g * 4) * 257 + 256;
    unsigned short pk[4];
    #pragma unroll
    for (int r = 0; r < 4; ++r) {
      float e = acc[r] + xq[(long)r * 257] * w256 + ebf;
      pk[r] = f2bf(e);
      ctx_acc += e;
    }
    if (m < 8) {
      long o = ((long)b * 1024 + m * 128 + band) * 128 + t0 + g * 4;
      *(ushort4*)(encbf + o) = make_ushort4(pk[0], pk[1], pk[2], pk[3]);
    }
  }
  // column(f) reduce: sum over g (lanes m, m+16, m+32, m+48), then over waves
  ctx_acc += __shfl_xor(ctx_acc, 16);
  ctx_acc += __shfl_xor(ctx_acc, 32);
  if (lane < 8) ctxred[w][lane] = ctx_acc;
  __syncthreads();
  if (tid < 8) {
    float sv = ctxred[0][tid] + ctxred[1][tid] + ctxred[2][tid] + ctxred[3][tid];
    ctx[(long)b * 1024 + tid * 128 + band] = sv;
  }
}

// ---------------- split-K gemm: partial y = h(4,1024) @ w[k-chunk] ----------------
template<int SUM2>
__global__ void gemm_p(const float* __restrict__ h, const float* __restrict__ w,
                       float* __restrict__ gpart) {
  __shared__ float hl[4][128];
  __shared__ float red[8][4][32];
  const int kc = blockIdx.y, jb = blockIdx.x, k0 = kc * 128;
  for (int i = threadIdx.x; i < 512; i += 256) {
    int bb = i >> 7, kk = i & 127;
    float v;
    if (SUM2) {
      int base = ((bb << 10) + k0 + kk) << 1;
      v = h[base] + h[base + 1];
    } else {
      v = h[(bb << 10) + k0 + kk];
    }
    hl[bb][kk] = v;
  }
  __syncthreads();
  const int jl = threadIdx.x & 31, kq = threadIdx.x >> 5;
  const int j = jb * 32 + jl;
  float a0 = 0, a1 = 0, a2 = 0, a3 = 0;
  const float* wp = w + (long)(k0 + kq * 16) * 1024 + j;
  #pragma unroll
  for (int k = 0; k < 16; ++k) {
    float wv = wp[(long)k * 1024];
    a0 += hl[0][kq * 16 + k] * wv;
    a1 += hl[1][kq * 16 + k] * wv;
    a2 += hl[2][kq * 16 + k] * wv;
    a3 += hl[3][kq * 16 + k] * wv;
  }
  red[kq][0][jl] = a0; red[kq][1][jl] = a1; red[kq][2][jl] = a2; red[kq][3][jl] = a3;
  __syncthreads();
  if (threadIdx.x < 128) {
    int bb = threadIdx.x >> 5, j2 = threadIdx.x & 31;
    float s = 0;
    #pragma unroll
    for (int q = 0; q < 8; ++q) s += red[q][bb][j2];
    gpart[((long)kc * 4 + bb) * 1024 + jb * 32 + j2] = s;
  }
}

// ---------------- sum split-K partials + bias + leaky + layernorm ----------------
__global__ void lnsum_kernel(const float* __restrict__ gpart, const float* __restrict__ bias,
                             const float* __restrict__ g, const float* __restrict__ be,
                             float* __restrict__ out) {
  int b = blockIdx.x;
  __shared__ float buf[1024];
  __shared__ float rs[4], rq[4];
  float s = 0, q = 0;
  #pragma unroll
  for (int i = 0; i < 4; ++i) {
    int j = threadIdx.x + i * 256;
    float v = bias[j];
    #pragma unroll
    for (int kc = 0; kc < 8; ++kc) v += gpart[((long)kc * 4 + b) * 1024 + j];
    v = leaky(v);
    buf[j] = v; s += v; q += v * v;
  }
  #pragma unroll
  for (int off = 32; off; off >>= 1) { s += __shfl_down(s, off); q += __shfl_down(q, off); }
  int wid = threadIdx.x >> 6, lane = threadIdx.x & 63;
  if (lane == 0) { rs[wid] = s; rq[wid] = q; }
  __syncthreads();
  float S = rs[0] + rs[1] + rs[2] + rs[3];
  float Q = rq[0] + rq[1] + rq[2] + rq[3];
  float mean = S * (1.f / 1024.f);
  float var = Q * (1.f / 1024.f) - mean * mean;
  float rstd = rsqrtf(var + 1e-5f);
  #pragma unroll
  for (int i = 0; i < 4; ++i) {
    int j = threadIdx.x + i * 256;
    out[b * 1024 + j] = (buf[j] - mean) * rstd * g[j] + be[j];
  }
}

// ---------------- final: ctx_out = sum partials + bias ----------------
__global__ void fin_kernel(const float* __restrict__ gpart, const float* __restrict__ bias,
                           float* __restrict__ out) {
  int i = blockIdx.x * 256 + threadIdx.x;   // 4096
  int b = i >> 10, j = i & 1023;
  float v = bias[j];
  #pragma unroll
  for (int kc = 0; kc < 8; ++kc) v += gpart[((long)kc * 4 + b) * 1024 + j];
  out[i] = v;
}

// ---------------- pack all 4 conv weights: f32 [Cout][Cin][7] -> bf16 [7][Cin/32][Cout][32] ----------------
DEV void pack_one(const float* __restrict__ w, unsigned short* __restrict__ wp,
                  int Cout, int Cin, int tid, int nthr) {
  int n = Cout * Cin * 7;
  int nCib = Cin >> 5;
  for (int i = tid; i < n; i += nthr) {
    int co = i / (Cin * 7);
    int r  = i - co * (Cin * 7);
    int ci = r / 7;
    int k  = r - ci * 7;
    wp[((long)(k * nCib + (ci >> 5)) * Cout + co) * 32 + (ci & 31)] = f2bf(w[i]);
  }
}
__global__ void wcvt_all(const float* __restrict__ w1, const float* __restrict__ w2,
                         const float* __restrict__ w3, const float* __restrict__ w4,
                         unsigned short* __restrict__ wbuf) {
  int tid = blockIdx.x * blockDim.x + threadIdx.x;
  int nthr = gridDim.x * blockDim.x;
  pack_one(w1, wbuf,           512, 1024, tid, nthr);
  pack_one(w2, wbuf + 3670016, 256,  512, tid, nthr);
  pack_one(w3, wbuf + 4587520, 128,  256, tid, nthr);
  pack_one(w4, wbuf + 4816896,  64,  128, tid, nthr);
}

// ---------------- implicit-GEMM conv1d via MFMA bf16 ----------------
template<int UPS, int SPLITK>
__global__ __launch_bounds__(256, 2)
void conv_mfma(const unsigned short* __restrict__ act,
               const unsigned short* __restrict__ wpack,
               float* __restrict__ outp,
               int Cin, int Cout, int Tout) {
  constexpr int NC = (UPS == 1) ? 70 : 18;
  const int Tin = Tout / UPS;
  const int cpb = Cin / SPLITK;
  const int ncib = cpb >> 5;
  const int nCibTot = Cin >> 5;
  const int nco = Cout >> 6, nt = Tout >> 6;

  int bid = blockIdx.x;
  const int sk = bid % SPLITK; bid /= SPLITK;
  const int tt = bid % nt;  bid /= nt;
  const int cot = bid % nco; bid /= nco;
  const int b = bid;
  const int t0 = tt << 6, co0 = cot << 6;
  const int ci0 = sk * cpb;

  extern __shared__ unsigned short lin[];    // [ncib][NC][40]

  const unsigned short* actb = act + ((long)b * Cin + ci0) * Tin;
  const int u_base = (UPS == 1) ? (t0 - 3) : ((t0 >> 2) - 1);
  const int total = cpb * NC;
  for (int i = threadIdx.x; i < total; i += 256) {
    int ci = i / NC, ul = i - ci * NC;
    int u = u_base + ul;
    unsigned short v = 0;
    if (u >= 0 && u < Tin) v = actb[(long)ci * Tin + u];
    lin[((ci >> 5) * NC + ul) * 40 + (ci & 31)] = v;
  }
  __syncthreads();

  const int lane = threadIdx.x & 63, w = threadIdx.x >> 6;
  const int m = lane & 15, g = lane >> 4;

  int boff[28];
  #pragma unroll
  for (int s = 0; s < 4; ++s) {
    #pragma unroll
    for (int k = 0; k < 7; ++k) {
      int row = (UPS == 1) ? (s * 16 + m + k)
                           : (s * 4 + ((m + k + 9) >> 2) - 2);
      boff[s * 7 + k] = row * 40 + g * 8;
    }
  }

  const long wlane = ((long)(co0 + w * 16 + m) * 4 + g) * 8;

  f32x4 acc[4];
  #pragma unroll
  for (int s = 0; s < 4; ++s) { acc[s][0] = 0.f; acc[s][1] = 0.f; acc[s][2] = 0.f; acc[s][3] = 0.f; }

  for (int cib = 0; cib < ncib; ++cib) {
    const unsigned short* lb = lin + cib * (NC * 40);
    const int cg = (ci0 >> 5) + cib;
    sh8 a[7];
    #pragma unroll
    for (int k = 0; k < 7; ++k)
      a[k] = *(const sh8*)(wpack + (long)(k * nCibTot + cg) * Cout * 32 + wlane);
    #pragma unroll
    for (int k = 0; k < 7; ++k) {
      #pragma unroll
      for (int s = 0; s < 4; ++s) {
        sh8 bfr = *(const sh8*)(lb + boff[s * 7 + k]);
        acc[s] = __builtin_amdgcn_mfma_f32_16x16x32_bf16(a[k], bfr, acc[s], 0, 0, 0);
      }
    }
  }

  float* op = outp + (((long)sk * 4 + b) * Cout + (co0 + w * 16 + g * 4)) * (long)Tout + t0 + m;
  #pragma unroll
  for (int r = 0; r < 4; ++r) {
    #pragma unroll
    for (int s = 0; s < 4; ++s)
      op[(long)r * Tout + s * 16] = acc[s][r];
  }
}

// ---------------- bn partial stats: grid (C, 4b) ----------------
__global__ void bnsum_kernel(const float* __restrict__ p, float* __restrict__ sp,
                             int C, int T, int SK) {
  int c = blockIdx.x, b = blockIdx.y;
  long stride = (long)4 * C * T;
  const float* r = p + ((long)b * C + c) * T;
  float s = 0, q = 0;
  for (int t = threadIdx.x; t < T; t += 256) {
    float v = r[t];
    for (int k = 1; k < SK; ++k) v += r[t + k * stride];
    s += v; q += v * v;
  }
  #pragma unroll
  for (int off = 32; off; off >>= 1) { s += __shfl_down(s, off); q += __shfl_down(q, off); }
  __shared__ float rs[4], rq[4];
  int wid = threadIdx.x >> 6, lane = threadIdx.x & 63;
  if (lane == 0) { rs[wid] = s; rq[wid] = q; }
  __syncthreads();
  if (threadIdx.x == 0) {
    sp[c * 4 + b] = rs[0] + rs[1] + rs[2] + rs[3];
    sp[C * 4 + c * 4 + b] = rq[0] + rq[1] + rq[2] + rq[3];
  }
}

// ---------------- bn finalize + leaky + sum split-K, emit bf16 ----------------
__global__ void bnapply_kernel(const float* __restrict__ p, const float* __restrict__ sp,
                               const float* __restrict__ g, const float* __restrict__ be,
                               unsigned short* __restrict__ obf,
                               int C, int tshift, int total, int SK) {
  int i = blockIdx.x * 256 + threadIdx.x;
  if (i >= total) return;
  float v = p[i];
  for (int k = 1; k < SK; ++k) v += p[i + (long)k * total];
  int c = (i >> tshift) & (C - 1);
  float s = sp[c * 4] + sp[c * 4 + 1] + sp[c * 4 + 2] + sp[c * 4 + 3];
  float q = sp[C * 4 + c * 4] + sp[C * 4 + c * 4 + 1] + sp[C * 4 + c * 4 + 2] + sp[C * 4 + c * 4 + 3];
  float n = (float)(4 << tshift);
  float mean = s / n;
  float var = q / n - mean * mean;
  float sc = g[c] * rsqrtf(var + 1e-5f);
  float sh = be[c] - mean * sc;
  obf[i] = f2bf(leaky(v * sc + sh));
}

// ---------------- final conv: phase-decomposed 3-tap ----------------
__global__ __launch_bounds__(256)
void conv5_kernel(const unsigned short* __restrict__ in, const float* __restrict__ wgt,
                  const float* __restrict__ bias, float* __restrict__ out, int Tout) {
  __shared__ unsigned short sv[64 * 66];
  __shared__ float wph[64 * 13];

  const int b = blockIdx.y;
  const int u0 = blockIdx.x * 64;
  const int Tin = Tout >> 2;
  const int tid = threadIdx.x;

  {
    int ci = tid >> 2, pp = tid & 3;
    float s0 = 0, s1 = 0, s2 = 0;
    #pragma unroll
    for (int k = 0; k < 7; ++k) {
      int d = (pp - 3 + k + 4) >> 2;
      float wv = wgt[ci * 7 + k];
      if (d == 0) s0 += wv; else if (d == 1) s1 += wv; else s2 += wv;
    }
    wph[ci * 13 + pp * 3 + 0] = s0;
    wph[ci * 13 + pp * 3 + 1] = s1;
    wph[ci * 13 + pp * 3 + 2] = s2;
  }

  const unsigned short* inb = in + (long)b * 64 * Tin;
  for (int i = tid; i < 64 * 66; i += 256) {
    int ci = i / 66, uu = i - ci * 66;
    int u = u0 - 1 + uu;
    unsigned short v = 0;
    if (u >= 0 && u < Tin) v = inb[(long)ci * Tin + u];
    sv[ci * 66 + uu] = v;
  }
  __syncthreads();

  const int ul = tid >> 2;
  const int chunk = tid & 3;
  float a0 = 0, a1 = 0, a2 = 0, a3 = 0;
  #pragma unroll
  for (int cc = 0; cc < 16; ++cc) {
    int ci = chunk * 16 + cc;
    float v0 = bf2f(sv[ci * 66 + ul]);
    float v1 = bf2f(sv[ci * 66 + ul + 1]);
    float v2 = bf2f(sv[ci * 66 + ul + 2]);
    const float* wp = wph + ci * 13;
    a0 += v0 * wp[0] + v1 * wp[1];
    a1 += v0 * wp[3] + v1 * wp[4] + v2 * wp[5];
    a2 += v0 * wp[6] + v1 * wp[7] + v2 * wp[8];
    a3 += v1 * wp[10] + v2 * wp[11];
  }
  #pragma unroll
  for (int msk = 1; msk <= 2; msk <<= 1) {
    a0 += __shfl_xor(a0, msk);
    a1 += __shfl_xor(a1, msk);
    a2 += __shfl_xor(a2, msk);
    a3 += __shfl_xor(a3, msk);
  }
  if (chunk == 0) {
    float bv = bias[0];
    float4 r = make_float4(a0 + bv, a1 + bv, a2 + bv, a3 + bv);
    *(float4*)(out + (long)b * Tout + (long)(u0 + ul) * 4) = r;
  }
}

extern "C" void kernel_launch(void* const* d_in, const int* in_sizes, int n_in,
                              void* d_out, int out_size, void* d_ws, size_t ws_size,
                              hipStream_t stream) {
  const float* x     = (const float*)d_in[0];
  // d_in[1] = atoms: dead (sparse_code result unused by outputs)
  const float* ew    = (const float*)d_in[2];
  const float* eb    = (const float*)d_in[3];
  const float* w1    = (const float*)d_in[4];
  const float* b1    = (const float*)d_in[5];
  const float* g1    = (const float*)d_in[6];
  const float* be1   = (const float*)d_in[7];
  const float* w2    = (const float*)d_in[8];
  const float* b2    = (const float*)d_in[9];
  const float* g2    = (const float*)d_in[10];
  const float* be2   = (const float*)d_in[11];
  const float* w3    = (const float*)d_in[12];
  const float* b3    = (const float*)d_in[13];
  const float* up_w1 = (const float*)d_in[14];
  const float* up_b1 = (const float*)d_in[15];
  const float* bn_g1 = (const float*)d_in[16];
  const float* bn_b1 = (const float*)d_in[17];
  const float* up_w2 = (const float*)d_in[18];
  const float* up_b2 = (const float*)d_in[19];
  const float* bn_g2 = (const float*)d_in[20];
  const float* bn_b2 = (const float*)d_in[21];
  const float* up_w3 = (const float*)d_in[22];
  const float* up_b3 = (const float*)d_in[23];
  const float* bn_g3 = (const float*)d_in[24];
  const float* bn_b3 = (const float*)d_in[25];
  const float* up_w4 = (const float*)d_in[26];
  const float* up_b4 = (const float*)d_in[27];
  const float* bn_g4 = (const float*)d_in[28];
  const float* bn_b4 = (const float*)d_in[29];
  const float* up_w5 = (const float*)d_in[30];
  const float* up_b5 = (const float*)d_in[31];

  float* out = (float*)d_out;              // [0,131072) = y, [131072,135168) = ctx_out

  float* ws = (float*)d_ws;
  float* ctxb   = ws;                      // 4096
  float* gpart  = ctxb + 4096;             // 32768
  float* t2     = gpart + 32768;           // 4096
  float* statsp = t2 + 4096;               // 4096
  float* pbuf   = statsp + 4096;           // 2097152
  unsigned short* encbf = (unsigned short*)(pbuf + 2097152);  // 524288 u16
  unsigned short* o1 = encbf + 524288;     // 262144 u16
  unsigned short* o2 = o1 + 262144;        // 524288 u16
  unsigned short* o3 = o2 + 524288;        // 1048576 u16
  unsigned short* o4 = o3 + 1048576;       // 2097152 u16
  unsigned short* wbuf = o4 + 2097152;     // 4874240 u16

  // embed (MFMA) + fused final ctx
  embed_mfma<<<512, 256, 0, stream>>>(x, ew, eb, encbf, ctxb);

  // ctx MLP (split-K gemms, deterministic partial sums)
  gemm_p<0><<<dim3(32, 8), 256, 0, stream>>>(ctxb, w1, gpart);
  lnsum_kernel<<<4, 256, 0, stream>>>(gpart, b1, g1, be1, t2);
  gemm_p<0><<<dim3(32, 8), 256, 0, stream>>>(t2, w2, gpart);
  lnsum_kernel<<<4, 256, 0, stream>>>(gpart, b2, g2, be2, t2);
  gemm_p<0><<<dim3(32, 8), 256, 0, stream>>>(t2, w3, gpart);
  fin_kernel<<<16, 256, 0, stream>>>(gpart, b3, out + 131072);

  // pack all conv weights in one launch
  wcvt_all<<<2048, 256, 0, stream>>>(up_w1, up_w2, up_w3, up_w4, wbuf);

  // ---- stage 1: (4,1024,128) -> (4,512,128), UPS=1, SK=8 ----
  conv_mfma<1, 8><<<512, 256, 22400, stream>>>(encbf, wbuf, pbuf, 1024, 512, 128);
  bnsum_kernel<<<dim3(512, 4), 256, 0, stream>>>(pbuf, statsp, 512, 128, 8);
  bnapply_kernel<<<1024, 256, 0, stream>>>(pbuf, statsp, bn_g1, bn_b1, o1, 512, 7, 262144, 8);

  // ---- stage 2: -up4-> (4,256,512), SK=4 ----
  conv_mfma<4, 4><<<512, 256, 5760, stream>>>(o1, wbuf + 3670016, pbuf, 512, 256, 512);
  bnsum_kernel<<<dim3(256, 4), 256, 0, stream>>>(pbuf, statsp, 256, 512, 4);
  bnapply_kernel<<<2048, 256, 0, stream>>>(pbuf, statsp, bn_g2, bn_b2, o2, 256, 9, 524288, 4);

  // ---- stage 3: -up4-> (4,128,2048), SK=2 ----
  conv_mfma<4, 2><<<512, 256, 5760, stream>>>(o2, wbuf + 4587520, pbuf, 256, 128, 2048);
  bnsum_kernel<<<dim3(128, 4), 256, 0, stream>>>(pbuf, statsp, 128, 2048, 2);
  bnapply_kernel<<<4096, 256, 0, stream>>>(pbuf, statsp, bn_g3, bn_b3, o3, 128, 11, 1048576, 2);

  // ---- stage 4: -up4-> (4,64,8192), SK=1 ----
  conv_mfma<4, 1><<<512, 256, 5760, stream>>>(o3, wbuf + 4816896, pbuf, 128, 64, 8192);
  bnsum_kernel<<<dim3(64, 4), 256, 0, stream>>>(pbuf, statsp, 64, 8192, 1);
  bnapply_kernel<<<8192, 256, 0, stream>>>(pbuf, statsp, bn_g4, bn_b4, o4, 64, 13, 2097152, 1);

  // ---- stage 5: -up4-> (4,1,32768), phase-decomposed ----
  conv5_kernel<<<dim3(128, 4), 256, 0, stream>>>(o4, up_w5, up_b5, out, 32768);
}